// Round 1
// baseline (272.838 us; speedup 1.0000x reference)
//
#include <hip/hip_runtime.h>

#define NT 1536
#define SCALE 0.17677669529663687f  // (256/8)^-0.5

// ---------------- GEMM: C[M,NN] = A[M,K] @ B[K,NN] (f32 row-major) ----------
__global__ __launch_bounds__(256) void gemm_f32(const float* __restrict__ A,
    const float* __restrict__ B, float* __restrict__ C, int M, int K, int NN)
{
    __shared__ float As[16][68];   // As[k][i]
    __shared__ float Bs[16][68];   // Bs[k][j]
    const int t = threadIdx.x;
    const int tx = t & 15, ty = t >> 4;
    const int i0 = blockIdx.y * 64, j0 = blockIdx.x * 64;
    float acc[4][4] = {};
    for (int k0 = 0; k0 < K; k0 += 16) {
        float4 av = *(const float4*)&A[(i0 + (t >> 2)) * K + k0 + (t & 3) * 4];
        float4 bv = *(const float4*)&B[(k0 + (t >> 4)) * NN + j0 + tx * 4];
        __syncthreads();
        As[(t & 3) * 4 + 0][t >> 2] = av.x;
        As[(t & 3) * 4 + 1][t >> 2] = av.y;
        As[(t & 3) * 4 + 2][t >> 2] = av.z;
        As[(t & 3) * 4 + 3][t >> 2] = av.w;
        *(float4*)&Bs[t >> 4][tx * 4] = bv;
        __syncthreads();
        #pragma unroll
        for (int kk = 0; kk < 16; kk++) {
            float4 a = *(const float4*)&As[kk][ty * 4];
            float4 b = *(const float4*)&Bs[kk][tx * 4];
            float ar_[4] = {a.x, a.y, a.z, a.w};
            float br_[4] = {b.x, b.y, b.z, b.w};
            #pragma unroll
            for (int r = 0; r < 4; r++)
                #pragma unroll
                for (int c = 0; c < 4; c++)
                    acc[r][c] += ar_[r] * br_[c];
        }
    }
    #pragma unroll
    for (int r = 0; r < 4; r++) {
        float4 o = {acc[r][0], acc[r][1], acc[r][2], acc[r][3]};
        *(float4*)&C[(i0 + ty * 4 + r) * NN + j0 + tx * 4] = o;
    }
}

// --------------- per-head L2 normalize along groups of gsize ----------------
__global__ __launch_bounds__(256) void normalize_k(const float* __restrict__ in,
    float* __restrict__ out, int rowlen, int gsize)
{
    const int row = blockIdx.x;
    for (int base = 0; base < rowlen; base += 256) {
        const int idx = base + (int)threadIdx.x;
        if (idx < rowlen) {
            float v = in[row * rowlen + idx];
            float s = v * v;
            for (int m = 1; m < gsize; m <<= 1)
                s += __shfl_xor(s, m);
            out[row * rowlen + idx] = v / sqrtf(s);
        }
    }
}

// --------------- sim/obj bit matrices + per-row obj counts ------------------
__global__ __launch_bounds__(256) void bits_kernel(
    const float* __restrict__ qkvn_cls, const float* __restrict__ qkvn_reg,
    const float* __restrict__ cls_score, const float* __restrict__ fg_score,
    unsigned* __restrict__ simbits, unsigned* __restrict__ objbits,
    int* __restrict__ objcnt)
{
    const int t = threadIdx.x;
    const int tx = t & 15, ty = t >> 4;
    const int i0 = blockIdx.y * 64, j0 = blockIdx.x * 64;
    __shared__ float Vit[32][68], Vjt[32][68];      // cls vn chunk (transposed)
    __shared__ float Writ[64][68], Wrjt[64][68];    // reg vrn full-K (transposed)
    __shared__ float csi[64], csj[64], fgi[64], fgj[64];
    __shared__ unsigned simw[64][2], objw[64][2];
    if (t < 64)       { csi[t] = cls_score[i0 + t]; fgi[t] = fg_score[i0 + t]; }
    else if (t < 128) { csj[t - 64] = cls_score[j0 + t - 64]; fgj[t - 64] = fg_score[j0 + t - 64]; }
    if (t < 128) simw[t >> 1][t & 1] = 0u;
    else         objw[(t - 128) >> 1][(t - 128) & 1] = 0u;
    // stage reg Vn (K=64), transposed
    #pragma unroll
    for (int q = 0; q < 4; q++) {
        const int fi = q * 256 + t;
        const int row = fi >> 4, c4 = (fi & 15) * 4;
        float4 vi = *(const float4*)&qkvn_reg[(i0 + row) * 192 + 128 + c4];
        float4 vj = *(const float4*)&qkvn_reg[(j0 + row) * 192 + 128 + c4];
        Writ[c4 + 0][row] = vi.x; Writ[c4 + 1][row] = vi.y; Writ[c4 + 2][row] = vi.z; Writ[c4 + 3][row] = vi.w;
        Wrjt[c4 + 0][row] = vj.x; Wrjt[c4 + 1][row] = vj.y; Wrjt[c4 + 2][row] = vj.z; Wrjt[c4 + 3][row] = vj.w;
    }
    float sc[4][4] = {}, sr[4][4] = {};
    for (int h = 0; h < 8; h++) {
        __syncthreads();
        #pragma unroll
        for (int q = 0; q < 2; q++) {
            const int fi = q * 256 + t;
            const int row = fi >> 3, c4 = (fi & 7) * 4;
            float4 vi = *(const float4*)&qkvn_cls[(i0 + row) * 768 + 512 + h * 32 + c4];
            float4 vj = *(const float4*)&qkvn_cls[(j0 + row) * 768 + 512 + h * 32 + c4];
            Vit[c4 + 0][row] = vi.x; Vit[c4 + 1][row] = vi.y; Vit[c4 + 2][row] = vi.z; Vit[c4 + 3][row] = vi.w;
            Vjt[c4 + 0][row] = vj.x; Vjt[c4 + 1][row] = vj.y; Vjt[c4 + 2][row] = vj.z; Vjt[c4 + 3][row] = vj.w;
        }
        __syncthreads();
        #pragma unroll 8
        for (int kk = 0; kk < 32; kk++) {
            float4 a = *(const float4*)&Vit[kk][ty * 4];
            float4 b = *(const float4*)&Vjt[kk][tx * 4];
            float ar_[4] = {a.x, a.y, a.z, a.w};
            float br_[4] = {b.x, b.y, b.z, b.w};
            #pragma unroll
            for (int r = 0; r < 4; r++)
                #pragma unroll
                for (int c = 0; c < 4; c++)
                    sc[r][c] += ar_[r] * br_[c];
        }
    }
    #pragma unroll 8
    for (int kk = 0; kk < 64; kk++) {
        float4 a = *(const float4*)&Writ[kk][ty * 4];
        float4 b = *(const float4*)&Wrjt[kk][tx * 4];
        float ar_[4] = {a.x, a.y, a.z, a.w};
        float br_[4] = {b.x, b.y, b.z, b.w};
        #pragma unroll
        for (int r = 0; r < 4; r++)
            #pragma unroll
            for (int c = 0; c < 4; c++)
                sr[r][c] += ar_[r] * br_[c];
    }
    #pragma unroll
    for (int r = 0; r < 4; r++) {
        unsigned snib = 0u, onib = 0u;
        const float ci = csi[ty * 4 + r], fgiv = fgi[ty * 4 + r];
        #pragma unroll
        for (int c = 0; c < 4; c++) {
            const float s  = sc[r][c] * 0.125f;
            const float so = sr[r][c] * 0.125f;
            const bool clsb = csj[tx * 4 + c] > ci - 0.1f;
            const bool fgb  = fgj[tx * 4 + c] > fgiv - 0.1f;
            const bool sim = (s > 0.75f) && clsb && fgb;
            const bool obj = (so > 0.75f) && sim;
            if (sim) snib |= 1u << c;
            if (obj) onib |= 1u << c;
        }
        const int rr = ty * 4 + r, w = tx >> 3, sh = (tx & 7) * 4;
        if (snib) atomicOr(&simw[rr][w], snib << sh);
        if (onib) atomicOr(&objw[rr][w], onib << sh);
    }
    __syncthreads();
    if (t < 128) {
        const int row = t >> 1, w = t & 1;
        simbits[(i0 + row) * 48 + blockIdx.x * 2 + w] = simw[row][w];
        objbits[(i0 + row) * 48 + blockIdx.x * 2 + w] = objw[row][w];
    }
    if (t < 64) {
        const int c = __popc(objw[t][0]) + __popc(objw[t][1]);
        if (c) atomicAdd(&objcnt[i0 + t], c);
    }
}

// --------------- softmax denominators (partial per j-tile) ------------------
__global__ __launch_bounds__(256) void denom_kernel(
    const float* __restrict__ qkvn_cls, const float* __restrict__ qkvn_reg,
    const float* __restrict__ cls_score,
    float* __restrict__ Dcpart, float* __restrict__ Drpart)
{
    const int t = threadIdx.x;
    const int tx = t & 15, ty = t >> 4;
    const int i0 = blockIdx.y * 64, j0 = blockIdx.x * 64;
    __shared__ float Qit[32][68], Kjt[32][68];
    __shared__ float Qrt[64][68], Krt[64][68];
    __shared__ float csi[64], csj[64];
    if (t < 64)       csi[t] = cls_score[i0 + t];
    else if (t < 128) csj[t - 64] = cls_score[j0 + t - 64];
    #pragma unroll
    for (int q = 0; q < 4; q++) {
        const int fi = q * 256 + t;
        const int row = fi >> 4, c4 = (fi & 15) * 4;
        float4 qv = *(const float4*)&qkvn_reg[(i0 + row) * 192 + 0 + c4];
        float4 kv = *(const float4*)&qkvn_reg[(j0 + row) * 192 + 64 + c4];
        Qrt[c4 + 0][row] = qv.x; Qrt[c4 + 1][row] = qv.y; Qrt[c4 + 2][row] = qv.z; Qrt[c4 + 3][row] = qv.w;
        Krt[c4 + 0][row] = kv.x; Krt[c4 + 1][row] = kv.y; Krt[c4 + 2][row] = kv.z; Krt[c4 + 3][row] = kv.w;
    }
    __syncthreads();
    float ci[4], cj4[4];
    #pragma unroll
    for (int r = 0; r < 4; r++) ci[r] = csi[ty * 4 + r];
    #pragma unroll
    for (int c = 0; c < 4; c++) cj4[c] = csj[tx * 4 + c];
    float Dcp[4][8] = {}, Drp[4][8] = {};
    #pragma unroll
    for (int h = 0; h < 8; h++) {
        __syncthreads();
        #pragma unroll
        for (int q = 0; q < 2; q++) {
            const int fi = q * 256 + t;
            const int row = fi >> 3, c4 = (fi & 7) * 4;
            float4 qv = *(const float4*)&qkvn_cls[(i0 + row) * 768 + 0   + h * 32 + c4];
            float4 kv = *(const float4*)&qkvn_cls[(j0 + row) * 768 + 256 + h * 32 + c4];
            Qit[c4 + 0][row] = qv.x; Qit[c4 + 1][row] = qv.y; Qit[c4 + 2][row] = qv.z; Qit[c4 + 3][row] = qv.w;
            Kjt[c4 + 0][row] = kv.x; Kjt[c4 + 1][row] = kv.y; Kjt[c4 + 2][row] = kv.z; Kjt[c4 + 3][row] = kv.w;
        }
        __syncthreads();
        float dc[4][4] = {};
        #pragma unroll 8
        for (int kk = 0; kk < 32; kk++) {
            float4 a = *(const float4*)&Qit[kk][ty * 4];
            float4 b = *(const float4*)&Kjt[kk][tx * 4];
            float ar_[4] = {a.x, a.y, a.z, a.w};
            float br_[4] = {b.x, b.y, b.z, b.w};
            #pragma unroll
            for (int r = 0; r < 4; r++)
                #pragma unroll
                for (int c = 0; c < 4; c++)
                    dc[r][c] += ar_[r] * br_[c];
        }
        #pragma unroll
        for (int c = 0; c < 4; c++) {
            const float cj = cj4[c];
            #pragma unroll
            for (int r = 0; r < 4; r++) {
                const bool mb = cj > ci[r] - 0.1f;
                const float lc = mb ? dc[r][c] * SCALE * cj : 0.0f;
                Dcp[r][h] += __expf(lc);
            }
        }
    }
    #pragma unroll
    for (int h = 0; h < 8; h++) {
        float dr[4][4] = {};
        #pragma unroll
        for (int k2 = 0; k2 < 8; k2++) {
            const int kk = h * 8 + k2;
            float4 a = *(const float4*)&Qrt[kk][ty * 4];
            float4 b = *(const float4*)&Krt[kk][tx * 4];
            float ar_[4] = {a.x, a.y, a.z, a.w};
            float br_[4] = {b.x, b.y, b.z, b.w};
            #pragma unroll
            for (int r = 0; r < 4; r++)
                #pragma unroll
                for (int c = 0; c < 4; c++)
                    dr[r][c] += ar_[r] * br_[c];
        }
        #pragma unroll
        for (int r = 0; r < 4; r++)
            #pragma unroll
            for (int c = 0; c < 4; c++)
                Drp[r][h] += __expf(dr[r][c] * SCALE);
    }
    #pragma unroll
    for (int r = 0; r < 4; r++)
        #pragma unroll
        for (int h = 0; h < 8; h++) {
            float v1 = Dcp[r][h], v2 = Drp[r][h];
            #pragma unroll
            for (int m = 1; m < 16; m <<= 1) { v1 += __shfl_xor(v1, m); v2 += __shfl_xor(v2, m); }
            if (tx == 0) {
                const int base = (blockIdx.x * NT + i0 + ty * 4 + r) * 8 + h;
                Dcpart[base] = v1;
                Drpart[base] = v2;
            }
        }
}

__global__ __launch_bounds__(256) void denom_reduce(
    const float* __restrict__ Dcpart, const float* __restrict__ Drpart,
    float* __restrict__ Dc, float* __restrict__ Dr)
{
    const int idx = blockIdx.x * 256 + threadIdx.x;  // 12288 = NT*8
    float s1 = 0.f, s2 = 0.f;
    for (int jt = 0; jt < 24; jt++) {
        s1 += Dcpart[jt * NT * 8 + idx];
        s2 += Drpart[jt * NT * 8 + idx];
    }
    Dc[idx] = s1;
    Dr[idx] = s2;
}

// --------------- sparse attn @ v using obj bit lists ------------------------
__global__ __launch_bounds__(256) void out_kernel(
    const float* __restrict__ qkv_cls, const float* __restrict__ qkvn_cls,
    const float* __restrict__ qkv_reg, const float* __restrict__ qkvn_reg,
    const float* __restrict__ cls_score,
    const unsigned* __restrict__ objbits, const int* __restrict__ objcnt,
    const float* __restrict__ Dc, const float* __restrict__ Dr,
    float* __restrict__ out_cls, float* __restrict__ out_reg)
{
    const int idx = blockIdx.x * 256 + threadIdx.x;  // 12288 = NT*8
    const int i = idx >> 3, h = idx & 7;
    float qn[32], qrn[8];
    #pragma unroll
    for (int d4 = 0; d4 < 8; d4++) {
        float4 v = *(const float4*)&qkvn_cls[i * 768 + h * 32 + d4 * 4];
        qn[d4 * 4 + 0] = v.x; qn[d4 * 4 + 1] = v.y; qn[d4 * 4 + 2] = v.z; qn[d4 * 4 + 3] = v.w;
    }
    #pragma unroll
    for (int d4 = 0; d4 < 2; d4++) {
        float4 v = *(const float4*)&qkvn_reg[i * 192 + h * 8 + d4 * 4];
        qrn[d4 * 4 + 0] = v.x; qrn[d4 * 4 + 1] = v.y; qrn[d4 * 4 + 2] = v.z; qrn[d4 * 4 + 3] = v.w;
    }
    float acc1[32] = {}, acc2[32] = {}, ar1[8] = {}, ar2[8] = {};
    for (int w = 0; w < 48; w++) {
        unsigned bits = objbits[i * 48 + w];
        while (bits) {
            const int b = __ffs(bits) - 1;
            bits &= bits - 1u;
            const int j = w * 32 + b;
            float kv[32], vv[32], krv[8], vrv[8];
            #pragma unroll
            for (int d4 = 0; d4 < 8; d4++) {
                float4 kk = *(const float4*)&qkvn_cls[j * 768 + 256 + h * 32 + d4 * 4];
                float4 v4 = *(const float4*)&qkv_cls [j * 768 + 512 + h * 32 + d4 * 4];
                kv[d4 * 4 + 0] = kk.x; kv[d4 * 4 + 1] = kk.y; kv[d4 * 4 + 2] = kk.z; kv[d4 * 4 + 3] = kk.w;
                vv[d4 * 4 + 0] = v4.x; vv[d4 * 4 + 1] = v4.y; vv[d4 * 4 + 2] = v4.z; vv[d4 * 4 + 3] = v4.w;
            }
            #pragma unroll
            for (int d4 = 0; d4 < 2; d4++) {
                float4 kk = *(const float4*)&qkvn_reg[j * 192 + 64  + h * 8 + d4 * 4];
                float4 v4 = *(const float4*)&qkv_reg [j * 192 + 128 + h * 8 + d4 * 4];
                krv[d4 * 4 + 0] = kk.x; krv[d4 * 4 + 1] = kk.y; krv[d4 * 4 + 2] = kk.z; krv[d4 * 4 + 3] = kk.w;
                vrv[d4 * 4 + 0] = v4.x; vrv[d4 * 4 + 1] = v4.y; vrv[d4 * 4 + 2] = v4.z; vrv[d4 * 4 + 3] = v4.w;
            }
            float dotc = 0.f, dotr = 0.f;
            #pragma unroll
            for (int d = 0; d < 32; d++) dotc += qn[d] * kv[d];
            #pragma unroll
            for (int d = 0; d < 8; d++) dotr += qrn[d] * krv[d];
            const float ec = __expf(dotc * SCALE * cls_score[j]);  // obj => cls_mask==1
            const float er = __expf(dotr * SCALE);
            #pragma unroll
            for (int d = 0; d < 32; d++) { acc1[d] += ec * vv[d]; acc2[d] += er * vv[d]; }
            #pragma unroll
            for (int d = 0; d < 8; d++)  { ar1[d] += ec * vrv[d]; ar2[d] += er * vrv[d]; }
        }
    }
    const float iDc = 1.0f / Dc[idx], iDr = 1.0f / Dr[idx];
    const float half_inv = 0.5f / (float)objcnt[i];
    #pragma unroll
    for (int d4 = 0; d4 < 8; d4++) {
        float4 o;
        o.x = (acc1[d4 * 4 + 0] * iDc + acc2[d4 * 4 + 0] * iDr) * half_inv;
        o.y = (acc1[d4 * 4 + 1] * iDc + acc2[d4 * 4 + 1] * iDr) * half_inv;
        o.z = (acc1[d4 * 4 + 2] * iDc + acc2[d4 * 4 + 2] * iDr) * half_inv;
        o.w = (acc1[d4 * 4 + 3] * iDc + acc2[d4 * 4 + 3] * iDr) * half_inv;
        *(float4*)&out_cls[i * 512 + h * 32 + d4 * 4] = o;
    }
    #pragma unroll
    for (int d4 = 0; d4 < 2; d4++) {
        float4 o;
        o.x = (ar1[d4 * 4 + 0] * iDc + ar2[d4 * 4 + 0] * iDr) * half_inv;
        o.y = (ar1[d4 * 4 + 1] * iDc + ar2[d4 * 4 + 1] * iDr) * half_inv;
        o.z = (ar1[d4 * 4 + 2] * iDc + ar2[d4 * 4 + 2] * iDr) * half_inv;
        o.w = (ar1[d4 * 4 + 3] * iDc + ar2[d4 * 4 + 3] * iDr) * half_inv;
        *(float4*)&out_reg[i * 128 + h * 8 + d4 * 4] = o;
    }
}

// --------------- expand bit matrices into 8 head copies ---------------------
__global__ __launch_bounds__(256) void expand_kernel(
    const unsigned* __restrict__ simbits, const unsigned* __restrict__ objbits,
    const int* __restrict__ objcnt,
    float* __restrict__ sim_out, float* __restrict__ obj_out)
{
    const int idx = blockIdx.x * 256 + threadIdx.x;  // NT*384
    const int i = idx / 384;
    const int j0 = (idx - i * 384) * 4;
    const unsigned sw = simbits[i * 48 + (j0 >> 5)] >> (j0 & 31);
    const unsigned ow = objbits[i * 48 + (j0 >> 5)] >> (j0 & 31);
    const float inv = 1.0f / (float)objcnt[i];
    float4 sv, ov;
    sv.x = (sw & 1u) ? 1.f : 0.f;  ov.x = (ow & 1u) ? inv : 0.f;
    sv.y = (sw & 2u) ? 1.f : 0.f;  ov.y = (ow & 2u) ? inv : 0.f;
    sv.z = (sw & 4u) ? 1.f : 0.f;  ov.z = (ow & 4u) ? inv : 0.f;
    sv.w = (sw & 8u) ? 1.f : 0.f;  ov.w = (ow & 8u) ? inv : 0.f;
    const int base = i * NT + j0;
    #pragma unroll
    for (int h = 0; h < 8; h++) {
        *(float4*)&sim_out[h * (NT * NT) + base] = sv;
        *(float4*)&obj_out[h * (NT * NT) + base] = ov;
    }
}

// --------------- concat copies ----------------------------------------------
__global__ __launch_bounds__(256) void copy_concat(
    const float* __restrict__ x_cls, const float* __restrict__ x_reg,
    float* __restrict__ out_cls, float* __restrict__ out_reg)
{
    const int idx = blockIdx.x * 256 + threadIdx.x;  // 122880
    if (idx < 98304) {
        const int i = idx >> 6, c = idx & 63;
        *(float4*)&out_cls[i * 512 + 256 + c * 4] = *(const float4*)&x_cls[i * 256 + c * 4];
    } else {
        const int u = idx - 98304;
        const int i = u >> 4, c = u & 15;
        *(float4*)&out_reg[i * 128 + 64 + c * 4] = *(const float4*)&x_reg[i * 64 + c * 4];
    }
}

extern "C" void kernel_launch(void* const* d_in, const int* in_sizes, int n_in,
                              void* d_out, int out_size, void* d_ws, size_t ws_size,
                              hipStream_t stream)
{
    (void)in_sizes; (void)n_in; (void)out_size; (void)ws_size;
    const float* x_cls     = (const float*)d_in[0];
    const float* x_reg     = (const float*)d_in[1];
    const float* cls_score = (const float*)d_in[2];
    const float* fg_score  = (const float*)d_in[3];
    const float* W_cls     = (const float*)d_in[4];
    const float* W_reg     = (const float*)d_in[5];

    float* out = (float*)d_out;
    float* out_cls = out;                  // 786432 floats
    float* out_reg = out + 786432;         // 196608 floats
    float* sim_out = out + 983040;         // 18874368 floats
    float* obj_out = out + 19857408;       // 18874368 floats

    // Large scratch lives inside output regions that are only written later:
    //  - qkv buffers in sim_out region (overwritten by expand_kernel at the end)
    //  - denominator partials in out_cls region (overwritten by out_kernel)
    float* qkv_cls  = sim_out;             // 1,179,648 floats
    float* qkvn_cls = sim_out + 1179648;   // 1,179,648
    float* qkv_reg  = sim_out + 2359296;   //   294,912
    float* qkvn_reg = sim_out + 2654208;   //   294,912  (total 2,949,120 < 18,874,368)
    float* Dcpart   = out_cls;             //   294,912 (24*1536*8)
    float* Drpart   = out_cls + 294912;    //   294,912 (ends 589,824 < 786,432)

    // Small scratch in d_ws (~0.7 MB)
    char* ws = (char*)d_ws;
    unsigned* simbits = (unsigned*)ws;             // 73728 words
    unsigned* objbits = simbits + 73728;           // 73728 words
    int*      objcnt  = (int*)(objbits + 73728);   // 1536
    float*    Dc      = (float*)(objcnt + 1536);   // 12288
    float*    Dr      = Dc + 12288;                // 12288

    hipMemsetAsync(objcnt, 0, 1536 * sizeof(int), stream);

    gemm_f32<<<dim3(12, 24), 256, 0, stream>>>(x_cls, W_cls, qkv_cls, NT, 256, 768);
    gemm_f32<<<dim3(3, 24), 256, 0, stream>>>(x_reg, W_reg, qkv_reg, NT, 64, 192);
    normalize_k<<<NT, 256, 0, stream>>>(qkv_cls, qkvn_cls, 768, 32);
    normalize_k<<<NT, 256, 0, stream>>>(qkv_reg, qkvn_reg, 192, 8);
    bits_kernel<<<dim3(24, 24), 256, 0, stream>>>(qkvn_cls, qkvn_reg, cls_score, fg_score,
                                                  simbits, objbits, objcnt);
    denom_kernel<<<dim3(24, 24), 256, 0, stream>>>(qkvn_cls, qkvn_reg, cls_score, Dcpart, Drpart);
    denom_reduce<<<48, 256, 0, stream>>>(Dcpart, Drpart, Dc, Dr);
    out_kernel<<<48, 256, 0, stream>>>(qkv_cls, qkvn_cls, qkv_reg, qkvn_reg, cls_score,
                                       objbits, objcnt, Dc, Dr, out_cls, out_reg);
    expand_kernel<<<2304, 256, 0, stream>>>(simbits, objbits, objcnt, sim_out, obj_out);
    copy_concat<<<480, 256, 0, stream>>>(x_cls, x_reg, out_cls, out_reg);
}

// Round 3
// 153.686 us; speedup vs baseline: 1.7753x; 1.7753x over previous
//
#include <hip/hip_runtime.h>

#define NT 1536
#define SCALE 0.17677669529663687f  // (256/8)^-0.5

// ---------------- GEMM: C[M,NN] = A[M,K] @ B[K,NN] (f32 row-major) ----------
__global__ __launch_bounds__(256) void gemm_f32(const float* __restrict__ A,
    const float* __restrict__ B, float* __restrict__ C, int M, int K, int NN)
{
    __shared__ float As[16][68];   // As[k][i]
    __shared__ float Bs[16][68];   // Bs[k][j]
    const int t = threadIdx.x;
    const int tx = t & 15, ty = t >> 4;
    const int i0 = blockIdx.y * 64, j0 = blockIdx.x * 64;
    float acc[4][4] = {};
    for (int k0 = 0; k0 < K; k0 += 16) {
        float4 av = *(const float4*)&A[(i0 + (t >> 2)) * K + k0 + (t & 3) * 4];
        float4 bv = *(const float4*)&B[(k0 + (t >> 4)) * NN + j0 + tx * 4];
        __syncthreads();
        As[(t & 3) * 4 + 0][t >> 2] = av.x;
        As[(t & 3) * 4 + 1][t >> 2] = av.y;
        As[(t & 3) * 4 + 2][t >> 2] = av.z;
        As[(t & 3) * 4 + 3][t >> 2] = av.w;
        *(float4*)&Bs[t >> 4][tx * 4] = bv;
        __syncthreads();
        #pragma unroll
        for (int kk = 0; kk < 16; kk++) {
            float4 a = *(const float4*)&As[kk][ty * 4];
            float4 b = *(const float4*)&Bs[kk][tx * 4];
            float ar_[4] = {a.x, a.y, a.z, a.w};
            float br_[4] = {b.x, b.y, b.z, b.w};
            #pragma unroll
            for (int r = 0; r < 4; r++)
                #pragma unroll
                for (int c = 0; c < 4; c++)
                    acc[r][c] += ar_[r] * br_[c];
        }
    }
    #pragma unroll
    for (int r = 0; r < 4; r++) {
        float4 o = {acc[r][0], acc[r][1], acc[r][2], acc[r][3]};
        *(float4*)&C[(i0 + ty * 4 + r) * NN + j0 + tx * 4] = o;
    }
}

// --------------- per-head L2 normalize along groups of gsize ----------------
__global__ __launch_bounds__(256) void normalize_k(const float* __restrict__ in,
    float* __restrict__ out, int rowlen, int gsize)
{
    const int row = blockIdx.x;
    for (int base = 0; base < rowlen; base += 256) {
        const int idx = base + (int)threadIdx.x;
        if (idx < rowlen) {
            float v = in[row * rowlen + idx];
            float s = v * v;
            for (int m = 1; m < gsize; m <<= 1)
                s += __shfl_xor(s, m);
            out[row * rowlen + idx] = v / sqrtf(s);
        }
    }
}

// --------------- sim/obj bit matrices + per-row obj counts ------------------
// GEMM-style 64x64 tile, two K loops (cls vn K=256, reg vrn K=64).
__global__ __launch_bounds__(256) void bits_v2(
    const float* __restrict__ qkvn_cls, const float* __restrict__ qkvn_reg,
    const float* __restrict__ cls_score, const float* __restrict__ fg_score,
    unsigned* __restrict__ simbits, unsigned* __restrict__ objbits,
    int* __restrict__ objcnt)
{
    __shared__ float As[16][68], Bs[16][68];
    __shared__ float csi[64], csj[64], fgi[64], fgj[64];
    __shared__ unsigned simw[64][2], objw[64][2];
    const int t = threadIdx.x;
    const int tx = t & 15, ty = t >> 4;
    const int i0 = blockIdx.y * 64, j0 = blockIdx.x * 64;
    if (t < 64)       { csi[t] = cls_score[i0 + t]; fgi[t] = fg_score[i0 + t]; }
    else if (t < 128) { csj[t - 64] = cls_score[j0 + t - 64]; fgj[t - 64] = fg_score[j0 + t - 64]; }
    // zero bit accumulators: 128 threads per array (64 rows x 2 words each)
    if (t < 128) simw[t >> 1][t & 1] = 0u;
    else         objw[(t - 128) >> 1][(t - 128) & 1] = 0u;
    float accc[4][4] = {}, accr[4][4] = {};
    // cls vn: row stride 768, offset 512, K=256
    for (int k0 = 0; k0 < 256; k0 += 16) {
        float4 av = *(const float4*)&qkvn_cls[(i0 + (t >> 2)) * 768 + 512 + k0 + (t & 3) * 4];
        float4 bv = *(const float4*)&qkvn_cls[(j0 + (t >> 2)) * 768 + 512 + k0 + (t & 3) * 4];
        __syncthreads();
        As[(t & 3) * 4 + 0][t >> 2] = av.x;
        As[(t & 3) * 4 + 1][t >> 2] = av.y;
        As[(t & 3) * 4 + 2][t >> 2] = av.z;
        As[(t & 3) * 4 + 3][t >> 2] = av.w;
        Bs[(t & 3) * 4 + 0][t >> 2] = bv.x;
        Bs[(t & 3) * 4 + 1][t >> 2] = bv.y;
        Bs[(t & 3) * 4 + 2][t >> 2] = bv.z;
        Bs[(t & 3) * 4 + 3][t >> 2] = bv.w;
        __syncthreads();
        #pragma unroll
        for (int kk = 0; kk < 16; kk++) {
            float4 a = *(const float4*)&As[kk][ty * 4];
            float4 b = *(const float4*)&Bs[kk][tx * 4];
            float ar_[4] = {a.x, a.y, a.z, a.w};
            float br_[4] = {b.x, b.y, b.z, b.w};
            #pragma unroll
            for (int r = 0; r < 4; r++)
                #pragma unroll
                for (int c = 0; c < 4; c++)
                    accc[r][c] += ar_[r] * br_[c];
        }
    }
    // reg vrn: row stride 192, offset 128, K=64
    for (int k0 = 0; k0 < 64; k0 += 16) {
        float4 av = *(const float4*)&qkvn_reg[(i0 + (t >> 2)) * 192 + 128 + k0 + (t & 3) * 4];
        float4 bv = *(const float4*)&qkvn_reg[(j0 + (t >> 2)) * 192 + 128 + k0 + (t & 3) * 4];
        __syncthreads();
        As[(t & 3) * 4 + 0][t >> 2] = av.x;
        As[(t & 3) * 4 + 1][t >> 2] = av.y;
        As[(t & 3) * 4 + 2][t >> 2] = av.z;
        As[(t & 3) * 4 + 3][t >> 2] = av.w;
        Bs[(t & 3) * 4 + 0][t >> 2] = bv.x;
        Bs[(t & 3) * 4 + 1][t >> 2] = bv.y;
        Bs[(t & 3) * 4 + 2][t >> 2] = bv.z;
        Bs[(t & 3) * 4 + 3][t >> 2] = bv.w;
        __syncthreads();
        #pragma unroll
        for (int kk = 0; kk < 16; kk++) {
            float4 a = *(const float4*)&As[kk][ty * 4];
            float4 b = *(const float4*)&Bs[kk][tx * 4];
            float ar_[4] = {a.x, a.y, a.z, a.w};
            float br_[4] = {b.x, b.y, b.z, b.w};
            #pragma unroll
            for (int r = 0; r < 4; r++)
                #pragma unroll
                for (int c = 0; c < 4; c++)
                    accr[r][c] += ar_[r] * br_[c];
        }
    }
    #pragma unroll
    for (int r = 0; r < 4; r++) {
        unsigned snib = 0u, onib = 0u;
        const float ci = csi[ty * 4 + r], fgiv = fgi[ty * 4 + r];
        #pragma unroll
        for (int c = 0; c < 4; c++) {
            const float s  = accc[r][c] * 0.125f;
            const float so = accr[r][c] * 0.125f;
            const bool clsb = csj[tx * 4 + c] > ci - 0.1f;
            const bool fgb  = fgj[tx * 4 + c] > fgiv - 0.1f;
            const bool sim = (s > 0.75f) && clsb && fgb;
            const bool obj = (so > 0.75f) && sim;
            if (sim) snib |= 1u << c;
            if (obj) onib |= 1u << c;
        }
        const int rr = ty * 4 + r, w = tx >> 3, sh = (tx & 7) * 4;
        if (snib) atomicOr(&simw[rr][w], snib << sh);
        if (onib) atomicOr(&objw[rr][w], onib << sh);
    }
    __syncthreads();
    if (t < 128) {
        const int row = t >> 1, w = t & 1;
        simbits[(i0 + row) * 48 + blockIdx.x * 2 + w] = simw[row][w];
        objbits[(i0 + row) * 48 + blockIdx.x * 2 + w] = objw[row][w];
    }
    if (t < 64) {
        const int c = __popc(objw[t][0]) + __popc(objw[t][1]);
        if (c) atomicAdd(&objcnt[i0 + t], c);
    }
}

// --------------- softmax denominators v2 ------------------------------------
// grid (24 i-tiles, 8 heads, 4 j-chunks); thread = (i_local, j-stripe of 4).
// q in registers, K staged in XOR-swizzled LDS (conflict-free both sides).
__global__ __launch_bounds__(256) void denom_v2(
    const float* __restrict__ qkvn_cls, const float* __restrict__ qkvn_reg,
    const float* __restrict__ cls_score,
    float* __restrict__ Dcpart, float* __restrict__ Drpart)
{
    const int t = threadIdx.x;
    const int it = blockIdx.x;   // i tile
    const int h  = blockIdx.y;   // head
    const int jc = blockIdx.z;   // j chunk (384 cols)
    const int i_local = t >> 2, jg = t & 3;
    const int i = it * 64 + i_local;

    __shared__ float Kc[128][32];  // col4 = d4 ^ (row&7), XOR involution
    __shared__ float Kr[128][8];   // col4 = d4 ^ (row&1)
    __shared__ float csj[128];

    float q[32], qr[8];
    #pragma unroll
    for (int d4 = 0; d4 < 8; d4++) {
        float4 v = *(const float4*)&qkvn_cls[i * 768 + h * 32 + d4 * 4];
        q[d4 * 4 + 0] = v.x; q[d4 * 4 + 1] = v.y; q[d4 * 4 + 2] = v.z; q[d4 * 4 + 3] = v.w;
    }
    #pragma unroll
    for (int d4 = 0; d4 < 2; d4++) {
        float4 v = *(const float4*)&qkvn_reg[i * 192 + h * 8 + d4 * 4];
        qr[d4 * 4 + 0] = v.x; qr[d4 * 4 + 1] = v.y; qr[d4 * 4 + 2] = v.z; qr[d4 * 4 + 3] = v.w;
    }
    const float ci = cls_score[i] - 0.1f;
    float sc = 0.f, sr = 0.f;

    for (int sb = 0; sb < 384; sb += 128) {
        const int jbase = jc * 384 + sb;
        __syncthreads();
        // stage Kc: 128 rows x 8 float4, swizzled
        #pragma unroll
        for (int u0 = 0; u0 < 4; u0++) {
            const int u = u0 * 256 + t;
            const int row = u >> 3, d4 = u & 7;
            const int c4 = d4 ^ (row & 7);
            float4 v = *(const float4*)&qkvn_cls[(jbase + row) * 768 + 256 + h * 32 + d4 * 4];
            *(float4*)&Kc[row][c4 * 4] = v;
        }
        // stage Kr: 128 rows x 2 float4, swizzled
        {
            const int row = t >> 1, d4 = t & 1;
            const int c4 = d4 ^ (row & 1);
            float4 v = *(const float4*)&qkvn_reg[(jbase + row) * 192 + 64 + h * 8 + d4 * 4];
            *(float4*)&Kr[row][c4 * 4] = v;
        }
        if (t < 128) csj[t] = cls_score[jbase + t];
        __syncthreads();
        for (int jj = 0; jj < 32; jj++) {
            const int j = jj * 4 + jg;
            float dc = 0.f, dr = 0.f;
            #pragma unroll
            for (int d4 = 0; d4 < 8; d4++) {
                const int c4 = d4 ^ (j & 7);
                float4 kv = *(const float4*)&Kc[j][c4 * 4];
                dc += q[d4 * 4 + 0] * kv.x + q[d4 * 4 + 1] * kv.y
                    + q[d4 * 4 + 2] * kv.z + q[d4 * 4 + 3] * kv.w;
            }
            #pragma unroll
            for (int d4 = 0; d4 < 2; d4++) {
                const int c4 = d4 ^ (j & 1);
                float4 kv = *(const float4*)&Kr[j][c4 * 4];
                dr += qr[d4 * 4 + 0] * kv.x + qr[d4 * 4 + 1] * kv.y
                    + qr[d4 * 4 + 2] * kv.z + qr[d4 * 4 + 3] * kv.w;
            }
            const float cj = csj[j];
            const float lc = (cj > ci) ? dc * SCALE * cj : 0.0f;
            sc += __expf(lc);
            sr += __expf(dr * SCALE);
        }
    }
    sc += __shfl_xor(sc, 1); sc += __shfl_xor(sc, 2);
    sr += __shfl_xor(sr, 1); sr += __shfl_xor(sr, 2);
    if (jg == 0) {
        Dcpart[jc * (NT * 8) + i * 8 + h] = sc;
        Drpart[jc * (NT * 8) + i * 8 + h] = sr;
    }
}

__global__ __launch_bounds__(256) void denom_reduce(
    const float* __restrict__ Dcpart, const float* __restrict__ Drpart,
    float* __restrict__ Dc, float* __restrict__ Dr)
{
    const int idx = blockIdx.x * 256 + threadIdx.x;  // 12288 = NT*8
    float s1 = 0.f, s2 = 0.f;
    for (int jt = 0; jt < 4; jt++) {
        s1 += Dcpart[jt * NT * 8 + idx];
        s2 += Drpart[jt * NT * 8 + idx];
    }
    Dc[idx] = s1;
    Dr[idx] = s2;
}

// --------------- sparse attn @ v using obj bit lists ------------------------
__global__ __launch_bounds__(256) void out_kernel(
    const float* __restrict__ qkv_cls, const float* __restrict__ qkvn_cls,
    const float* __restrict__ qkv_reg, const float* __restrict__ qkvn_reg,
    const float* __restrict__ cls_score,
    const unsigned* __restrict__ objbits, const int* __restrict__ objcnt,
    const float* __restrict__ Dc, const float* __restrict__ Dr,
    float* __restrict__ out_cls, float* __restrict__ out_reg)
{
    const int idx = blockIdx.x * 256 + threadIdx.x;  // 12288 = NT*8
    const int i = idx >> 3, h = idx & 7;
    float qn[32], qrn[8];
    #pragma unroll
    for (int d4 = 0; d4 < 8; d4++) {
        float4 v = *(const float4*)&qkvn_cls[i * 768 + h * 32 + d4 * 4];
        qn[d4 * 4 + 0] = v.x; qn[d4 * 4 + 1] = v.y; qn[d4 * 4 + 2] = v.z; qn[d4 * 4 + 3] = v.w;
    }
    #pragma unroll
    for (int d4 = 0; d4 < 2; d4++) {
        float4 v = *(const float4*)&qkvn_reg[i * 192 + h * 8 + d4 * 4];
        qrn[d4 * 4 + 0] = v.x; qrn[d4 * 4 + 1] = v.y; qrn[d4 * 4 + 2] = v.z; qrn[d4 * 4 + 3] = v.w;
    }
    float acc1[32] = {}, acc2[32] = {}, ar1[8] = {}, ar2[8] = {};
    for (int w = 0; w < 48; w++) {
        unsigned bits = objbits[i * 48 + w];
        while (bits) {
            const int b = __ffs(bits) - 1;
            bits &= bits - 1u;
            const int j = w * 32 + b;
            float kv[32], vv[32], krv[8], vrv[8];
            #pragma unroll
            for (int d4 = 0; d4 < 8; d4++) {
                float4 kk = *(const float4*)&qkvn_cls[j * 768 + 256 + h * 32 + d4 * 4];
                float4 v4 = *(const float4*)&qkv_cls [j * 768 + 512 + h * 32 + d4 * 4];
                kv[d4 * 4 + 0] = kk.x; kv[d4 * 4 + 1] = kk.y; kv[d4 * 4 + 2] = kk.z; kv[d4 * 4 + 3] = kk.w;
                vv[d4 * 4 + 0] = v4.x; vv[d4 * 4 + 1] = v4.y; vv[d4 * 4 + 2] = v4.z; vv[d4 * 4 + 3] = v4.w;
            }
            #pragma unroll
            for (int d4 = 0; d4 < 2; d4++) {
                float4 kk = *(const float4*)&qkvn_reg[j * 192 + 64  + h * 8 + d4 * 4];
                float4 v4 = *(const float4*)&qkv_reg [j * 192 + 128 + h * 8 + d4 * 4];
                krv[d4 * 4 + 0] = kk.x; krv[d4 * 4 + 1] = kk.y; krv[d4 * 4 + 2] = kk.z; krv[d4 * 4 + 3] = kk.w;
                vrv[d4 * 4 + 0] = v4.x; vrv[d4 * 4 + 1] = v4.y; vrv[d4 * 4 + 2] = v4.z; vrv[d4 * 4 + 3] = v4.w;
            }
            float dotc = 0.f, dotr = 0.f;
            #pragma unroll
            for (int d = 0; d < 32; d++) dotc += qn[d] * kv[d];
            #pragma unroll
            for (int d = 0; d < 8; d++) dotr += qrn[d] * krv[d];
            const float ec = __expf(dotc * SCALE * cls_score[j]);  // obj => cls_mask==1
            const float er = __expf(dotr * SCALE);
            #pragma unroll
            for (int d = 0; d < 32; d++) { acc1[d] += ec * vv[d]; acc2[d] += er * vv[d]; }
            #pragma unroll
            for (int d = 0; d < 8; d++)  { ar1[d] += ec * vrv[d]; ar2[d] += er * vrv[d]; }
        }
    }
    const float iDc = 1.0f / Dc[idx], iDr = 1.0f / Dr[idx];
    const float half_inv = 0.5f / (float)objcnt[i];
    #pragma unroll
    for (int d4 = 0; d4 < 8; d4++) {
        float4 o;
        o.x = (acc1[d4 * 4 + 0] * iDc + acc2[d4 * 4 + 0] * iDr) * half_inv;
        o.y = (acc1[d4 * 4 + 1] * iDc + acc2[d4 * 4 + 1] * iDr) * half_inv;
        o.z = (acc1[d4 * 4 + 2] * iDc + acc2[d4 * 4 + 2] * iDr) * half_inv;
        o.w = (acc1[d4 * 4 + 3] * iDc + acc2[d4 * 4 + 3] * iDr) * half_inv;
        *(float4*)&out_cls[i * 512 + h * 32 + d4 * 4] = o;
    }
    #pragma unroll
    for (int d4 = 0; d4 < 2; d4++) {
        float4 o;
        o.x = (ar1[d4 * 4 + 0] * iDc + ar2[d4 * 4 + 0] * iDr) * half_inv;
        o.y = (ar1[d4 * 4 + 1] * iDc + ar2[d4 * 4 + 1] * iDr) * half_inv;
        o.z = (ar1[d4 * 4 + 2] * iDc + ar2[d4 * 4 + 2] * iDr) * half_inv;
        o.w = (ar1[d4 * 4 + 3] * iDc + ar2[d4 * 4 + 3] * iDr) * half_inv;
        *(float4*)&out_reg[i * 128 + h * 8 + d4 * 4] = o;
    }
}

// --------------- expand bit matrices into 8 head copies ---------------------
__global__ __launch_bounds__(256) void expand_kernel(
    const unsigned* __restrict__ simbits, const unsigned* __restrict__ objbits,
    const int* __restrict__ objcnt,
    float* __restrict__ sim_out, float* __restrict__ obj_out)
{
    const int idx = blockIdx.x * 256 + threadIdx.x;  // NT*384
    const int i = idx / 384;
    const int j0 = (idx - i * 384) * 4;
    const unsigned sw = simbits[i * 48 + (j0 >> 5)] >> (j0 & 31);
    const unsigned ow = objbits[i * 48 + (j0 >> 5)] >> (j0 & 31);
    const float inv = 1.0f / (float)objcnt[i];
    float4 sv, ov;
    sv.x = (sw & 1u) ? 1.f : 0.f;  ov.x = (ow & 1u) ? inv : 0.f;
    sv.y = (sw & 2u) ? 1.f : 0.f;  ov.y = (ow & 2u) ? inv : 0.f;
    sv.z = (sw & 4u) ? 1.f : 0.f;  ov.z = (ow & 4u) ? inv : 0.f;
    sv.w = (sw & 8u) ? 1.f : 0.f;  ov.w = (ow & 8u) ? inv : 0.f;
    const int base = i * NT + j0;
    #pragma unroll
    for (int h = 0; h < 8; h++) {
        *(float4*)&sim_out[h * (NT * NT) + base] = sv;
        *(float4*)&obj_out[h * (NT * NT) + base] = ov;
    }
}

// --------------- concat copies ----------------------------------------------
__global__ __launch_bounds__(256) void copy_concat(
    const float* __restrict__ x_cls, const float* __restrict__ x_reg,
    float* __restrict__ out_cls, float* __restrict__ out_reg)
{
    const int idx = blockIdx.x * 256 + threadIdx.x;  // 122880
    if (idx < 98304) {
        const int i = idx >> 6, c = idx & 63;
        *(float4*)&out_cls[i * 512 + 256 + c * 4] = *(const float4*)&x_cls[i * 256 + c * 4];
    } else {
        const int u = idx - 98304;
        const int i = u >> 4, c = u & 15;
        *(float4*)&out_reg[i * 128 + 64 + c * 4] = *(const float4*)&x_reg[i * 64 + c * 4];
    }
}

extern "C" void kernel_launch(void* const* d_in, const int* in_sizes, int n_in,
                              void* d_out, int out_size, void* d_ws, size_t ws_size,
                              hipStream_t stream)
{
    (void)in_sizes; (void)n_in; (void)out_size; (void)ws_size;
    const float* x_cls     = (const float*)d_in[0];
    const float* x_reg     = (const float*)d_in[1];
    const float* cls_score = (const float*)d_in[2];
    const float* fg_score  = (const float*)d_in[3];
    const float* W_cls     = (const float*)d_in[4];
    const float* W_reg     = (const float*)d_in[5];

    float* out = (float*)d_out;
    float* out_cls = out;                  // 786432 floats
    float* out_reg = out + 786432;         // 196608 floats
    float* sim_out = out + 983040;         // 18874368 floats
    float* obj_out = out + 19857408;       // 18874368 floats

    // Large scratch inside output regions that are written later:
    float* qkv_cls  = sim_out;             // 1,179,648 floats
    float* qkvn_cls = sim_out + 1179648;   // 1,179,648
    float* qkv_reg  = sim_out + 2359296;   //   294,912
    float* qkvn_reg = sim_out + 2654208;   //   294,912
    float* Dcpart   = out_cls;             //    49,152 (4*1536*8)
    float* Drpart   = out_cls + 49152;     //    49,152 (ends 98,304 < 786,432)

    // Small scratch in d_ws (~0.7 MB)
    char* ws = (char*)d_ws;
    unsigned* simbits = (unsigned*)ws;             // 73728 words
    unsigned* objbits = simbits + 73728;           // 73728 words
    int*      objcnt  = (int*)(objbits + 73728);   // 1536
    float*    Dc      = (float*)(objcnt + 1536);   // 12288
    float*    Dr      = Dc + 12288;                // 12288

    hipMemsetAsync(objcnt, 0, 1536 * sizeof(int), stream);

    gemm_f32<<<dim3(12, 24), 256, 0, stream>>>(x_cls, W_cls, qkv_cls, NT, 256, 768);
    gemm_f32<<<dim3(3, 24), 256, 0, stream>>>(x_reg, W_reg, qkv_reg, NT, 64, 192);
    normalize_k<<<NT, 256, 0, stream>>>(qkv_cls, qkvn_cls, 768, 32);
    normalize_k<<<NT, 256, 0, stream>>>(qkv_reg, qkvn_reg, 192, 8);
    bits_v2<<<dim3(24, 24), 256, 0, stream>>>(qkvn_cls, qkvn_reg, cls_score, fg_score,
                                              simbits, objbits, objcnt);
    denom_v2<<<dim3(24, 8, 4), 256, 0, stream>>>(qkvn_cls, qkvn_reg, cls_score, Dcpart, Drpart);
    denom_reduce<<<48, 256, 0, stream>>>(Dcpart, Drpart, Dc, Dr);
    out_kernel<<<48, 256, 0, stream>>>(qkv_cls, qkvn_cls, qkv_reg, qkvn_reg, cls_score,
                                       objbits, objcnt, Dc, Dr, out_cls, out_reg);
    expand_kernel<<<2304, 256, 0, stream>>>(simbits, objbits, objcnt, sim_out, obj_out);
    copy_concat<<<480, 256, 0, stream>>>(x_cls, x_reg, out_cls, out_reg);
}

// Round 4
// 150.245 us; speedup vs baseline: 1.8160x; 1.0229x over previous
//
#include <hip/hip_runtime.h>

#define NT 1536
#define SCALE 0.17677669529663687f  // (256/8)^-0.5

// ---------------- GEMM: C[M,NN] = A[M,K] @ B[K,NN] (f32 row-major) ----------
__global__ __launch_bounds__(256) void gemm_f32(const float* __restrict__ A,
    const float* __restrict__ B, float* __restrict__ C, int M, int K, int NN)
{
    __shared__ float As[16][68];   // As[k][i]
    __shared__ float Bs[16][68];   // Bs[k][j]
    const int t = threadIdx.x;
    const int tx = t & 15, ty = t >> 4;
    const int i0 = blockIdx.y * 64, j0 = blockIdx.x * 64;
    float acc[4][4] = {};
    for (int k0 = 0; k0 < K; k0 += 16) {
        float4 av = *(const float4*)&A[(i0 + (t >> 2)) * K + k0 + (t & 3) * 4];
        float4 bv = *(const float4*)&B[(k0 + (t >> 4)) * NN + j0 + tx * 4];
        __syncthreads();
        As[(t & 3) * 4 + 0][t >> 2] = av.x;
        As[(t & 3) * 4 + 1][t >> 2] = av.y;
        As[(t & 3) * 4 + 2][t >> 2] = av.z;
        As[(t & 3) * 4 + 3][t >> 2] = av.w;
        *(float4*)&Bs[t >> 4][tx * 4] = bv;
        __syncthreads();
        #pragma unroll
        for (int kk = 0; kk < 16; kk++) {
            float4 a = *(const float4*)&As[kk][ty * 4];
            float4 b = *(const float4*)&Bs[kk][tx * 4];
            float ar_[4] = {a.x, a.y, a.z, a.w};
            float br_[4] = {b.x, b.y, b.z, b.w};
            #pragma unroll
            for (int r = 0; r < 4; r++)
                #pragma unroll
                for (int c = 0; c < 4; c++)
                    acc[r][c] += ar_[r] * br_[c];
        }
    }
    #pragma unroll
    for (int r = 0; r < 4; r++) {
        float4 o = {acc[r][0], acc[r][1], acc[r][2], acc[r][3]};
        *(float4*)&C[(i0 + ty * 4 + r) * NN + j0 + tx * 4] = o;
    }
}

// --------------- per-head L2 normalize along groups of gsize ----------------
__global__ __launch_bounds__(256) void normalize_k(const float* __restrict__ in,
    float* __restrict__ out, int rowlen, int gsize)
{
    const int row = blockIdx.x;
    for (int base = 0; base < rowlen; base += 256) {
        const int idx = base + (int)threadIdx.x;
        if (idx < rowlen) {
            float v = in[row * rowlen + idx];
            float s = v * v;
            for (int m = 1; m < gsize; m <<= 1)
                s += __shfl_xor(s, m);
            out[row * rowlen + idx] = v / sqrtf(s);
        }
    }
}

// --------------- sim/obj bit matrices ---------------------------------------
// GEMM-style 64x64 tile, two K loops (cls vn K=256, reg vrn K=64).
__global__ __launch_bounds__(256) void bits_v2(
    const float* __restrict__ qkvn_cls, const float* __restrict__ qkvn_reg,
    const float* __restrict__ cls_score, const float* __restrict__ fg_score,
    unsigned* __restrict__ simbits, unsigned* __restrict__ objbits)
{
    __shared__ float As[16][68], Bs[16][68];
    __shared__ float csi[64], csj[64], fgi[64], fgj[64];
    __shared__ unsigned simw[64][2], objw[64][2];
    const int t = threadIdx.x;
    const int tx = t & 15, ty = t >> 4;
    const int i0 = blockIdx.y * 64, j0 = blockIdx.x * 64;
    if (t < 64)       { csi[t] = cls_score[i0 + t]; fgi[t] = fg_score[i0 + t]; }
    else if (t < 128) { csj[t - 64] = cls_score[j0 + t - 64]; fgj[t - 64] = fg_score[j0 + t - 64]; }
    // zero bit accumulators: 128 threads per array (64 rows x 2 words each)
    if (t < 128) simw[t >> 1][t & 1] = 0u;
    else         objw[(t - 128) >> 1][(t - 128) & 1] = 0u;
    float accc[4][4] = {}, accr[4][4] = {};
    // cls vn: row stride 768, offset 512, K=256
    for (int k0 = 0; k0 < 256; k0 += 16) {
        float4 av = *(const float4*)&qkvn_cls[(i0 + (t >> 2)) * 768 + 512 + k0 + (t & 3) * 4];
        float4 bv = *(const float4*)&qkvn_cls[(j0 + (t >> 2)) * 768 + 512 + k0 + (t & 3) * 4];
        __syncthreads();
        As[(t & 3) * 4 + 0][t >> 2] = av.x;
        As[(t & 3) * 4 + 1][t >> 2] = av.y;
        As[(t & 3) * 4 + 2][t >> 2] = av.z;
        As[(t & 3) * 4 + 3][t >> 2] = av.w;
        Bs[(t & 3) * 4 + 0][t >> 2] = bv.x;
        Bs[(t & 3) * 4 + 1][t >> 2] = bv.y;
        Bs[(t & 3) * 4 + 2][t >> 2] = bv.z;
        Bs[(t & 3) * 4 + 3][t >> 2] = bv.w;
        __syncthreads();
        #pragma unroll
        for (int kk = 0; kk < 16; kk++) {
            float4 a = *(const float4*)&As[kk][ty * 4];
            float4 b = *(const float4*)&Bs[kk][tx * 4];
            float ar_[4] = {a.x, a.y, a.z, a.w};
            float br_[4] = {b.x, b.y, b.z, b.w};
            #pragma unroll
            for (int r = 0; r < 4; r++)
                #pragma unroll
                for (int c = 0; c < 4; c++)
                    accc[r][c] += ar_[r] * br_[c];
        }
    }
    // reg vrn: row stride 192, offset 128, K=64
    for (int k0 = 0; k0 < 64; k0 += 16) {
        float4 av = *(const float4*)&qkvn_reg[(i0 + (t >> 2)) * 192 + 128 + k0 + (t & 3) * 4];
        float4 bv = *(const float4*)&qkvn_reg[(j0 + (t >> 2)) * 192 + 128 + k0 + (t & 3) * 4];
        __syncthreads();
        As[(t & 3) * 4 + 0][t >> 2] = av.x;
        As[(t & 3) * 4 + 1][t >> 2] = av.y;
        As[(t & 3) * 4 + 2][t >> 2] = av.z;
        As[(t & 3) * 4 + 3][t >> 2] = av.w;
        Bs[(t & 3) * 4 + 0][t >> 2] = bv.x;
        Bs[(t & 3) * 4 + 1][t >> 2] = bv.y;
        Bs[(t & 3) * 4 + 2][t >> 2] = bv.z;
        Bs[(t & 3) * 4 + 3][t >> 2] = bv.w;
        __syncthreads();
        #pragma unroll
        for (int kk = 0; kk < 16; kk++) {
            float4 a = *(const float4*)&As[kk][ty * 4];
            float4 b = *(const float4*)&Bs[kk][tx * 4];
            float ar_[4] = {a.x, a.y, a.z, a.w};
            float br_[4] = {b.x, b.y, b.z, b.w};
            #pragma unroll
            for (int r = 0; r < 4; r++)
                #pragma unroll
                for (int c = 0; c < 4; c++)
                    accr[r][c] += ar_[r] * br_[c];
        }
    }
    #pragma unroll
    for (int r = 0; r < 4; r++) {
        unsigned snib = 0u, onib = 0u;
        const float ci = csi[ty * 4 + r], fgiv = fgi[ty * 4 + r];
        #pragma unroll
        for (int c = 0; c < 4; c++) {
            const float s  = accc[r][c] * 0.125f;
            const float so = accr[r][c] * 0.125f;
            const bool clsb = csj[tx * 4 + c] > ci - 0.1f;
            const bool fgb  = fgj[tx * 4 + c] > fgiv - 0.1f;
            const bool sim = (s > 0.75f) && clsb && fgb;
            const bool obj = (so > 0.75f) && sim;
            if (sim) snib |= 1u << c;
            if (obj) onib |= 1u << c;
        }
        const int rr = ty * 4 + r, w = tx >> 3, sh = (tx & 7) * 4;
        if (snib) atomicOr(&simw[rr][w], snib << sh);
        if (onib) atomicOr(&objw[rr][w], onib << sh);
    }
    __syncthreads();
    if (t < 128) {
        const int row = t >> 1, w = t & 1;
        simbits[(i0 + row) * 48 + blockIdx.x * 2 + w] = simw[row][w];
        objbits[(i0 + row) * 48 + blockIdx.x * 2 + w] = objw[row][w];
    }
}

// --------------- per-row obj counts from bit matrix -------------------------
__global__ __launch_bounds__(256) void count_kernel(
    const unsigned* __restrict__ objbits, int* __restrict__ objcnt)
{
    const int i = blockIdx.x * 256 + threadIdx.x;  // 1536
    int c = 0;
    #pragma unroll 8
    for (int w = 0; w < 48; w++) c += __popc(objbits[i * 48 + w]);
    objcnt[i] = c;
}

// --------------- softmax denominators v2 ------------------------------------
// grid (24 i-tiles, 8 heads, 4 j-chunks); thread = (i_local, j-stripe of 4).
// q in registers, K staged in XOR-swizzled LDS (conflict-free both sides).
__global__ __launch_bounds__(256) void denom_v2(
    const float* __restrict__ qkvn_cls, const float* __restrict__ qkvn_reg,
    const float* __restrict__ cls_score,
    float* __restrict__ Dcpart, float* __restrict__ Drpart)
{
    const int t = threadIdx.x;
    const int it = blockIdx.x;   // i tile
    const int h  = blockIdx.y;   // head
    const int jc = blockIdx.z;   // j chunk (384 cols)
    const int i_local = t >> 2, jg = t & 3;
    const int i = it * 64 + i_local;

    __shared__ float Kc[128][32];  // col4 = d4 ^ (row&7), XOR involution
    __shared__ float Kr[128][8];   // col4 = d4 ^ (row&1)
    __shared__ float csj[128];

    float q[32], qr[8];
    #pragma unroll
    for (int d4 = 0; d4 < 8; d4++) {
        float4 v = *(const float4*)&qkvn_cls[i * 768 + h * 32 + d4 * 4];
        q[d4 * 4 + 0] = v.x; q[d4 * 4 + 1] = v.y; q[d4 * 4 + 2] = v.z; q[d4 * 4 + 3] = v.w;
    }
    #pragma unroll
    for (int d4 = 0; d4 < 2; d4++) {
        float4 v = *(const float4*)&qkvn_reg[i * 192 + h * 8 + d4 * 4];
        qr[d4 * 4 + 0] = v.x; qr[d4 * 4 + 1] = v.y; qr[d4 * 4 + 2] = v.z; qr[d4 * 4 + 3] = v.w;
    }
    const float ci = cls_score[i] - 0.1f;
    float sc = 0.f, sr = 0.f;

    for (int sb = 0; sb < 384; sb += 128) {
        const int jbase = jc * 384 + sb;
        __syncthreads();
        // stage Kc: 128 rows x 8 float4, swizzled
        #pragma unroll
        for (int u0 = 0; u0 < 4; u0++) {
            const int u = u0 * 256 + t;
            const int row = u >> 3, d4 = u & 7;
            const int c4 = d4 ^ (row & 7);
            float4 v = *(const float4*)&qkvn_cls[(jbase + row) * 768 + 256 + h * 32 + d4 * 4];
            *(float4*)&Kc[row][c4 * 4] = v;
        }
        // stage Kr: 128 rows x 2 float4, swizzled
        {
            const int row = t >> 1, d4 = t & 1;
            const int c4 = d4 ^ (row & 1);
            float4 v = *(const float4*)&qkvn_reg[(jbase + row) * 192 + 64 + h * 8 + d4 * 4];
            *(float4*)&Kr[row][c4 * 4] = v;
        }
        if (t < 128) csj[t] = cls_score[jbase + t];
        __syncthreads();
        for (int jj = 0; jj < 32; jj++) {
            const int j = jj * 4 + jg;
            float dc = 0.f, dr = 0.f;
            #pragma unroll
            for (int d4 = 0; d4 < 8; d4++) {
                const int c4 = d4 ^ (j & 7);
                float4 kv = *(const float4*)&Kc[j][c4 * 4];
                dc += q[d4 * 4 + 0] * kv.x + q[d4 * 4 + 1] * kv.y
                    + q[d4 * 4 + 2] * kv.z + q[d4 * 4 + 3] * kv.w;
            }
            #pragma unroll
            for (int d4 = 0; d4 < 2; d4++) {
                const int c4 = d4 ^ (j & 1);
                float4 kv = *(const float4*)&Kr[j][c4 * 4];
                dr += qr[d4 * 4 + 0] * kv.x + qr[d4 * 4 + 1] * kv.y
                    + qr[d4 * 4 + 2] * kv.z + qr[d4 * 4 + 3] * kv.w;
            }
            const float cj = csj[j];
            const float lc = (cj > ci) ? dc * SCALE * cj : 0.0f;
            sc += __expf(lc);
            sr += __expf(dr * SCALE);
        }
    }
    sc += __shfl_xor(sc, 1); sc += __shfl_xor(sc, 2);
    sr += __shfl_xor(sr, 1); sr += __shfl_xor(sr, 2);
    if (jg == 0) {
        Dcpart[jc * (NT * 8) + i * 8 + h] = sc;
        Drpart[jc * (NT * 8) + i * 8 + h] = sr;
    }
}

// --------------- sparse attn @ v + fused denom-reduce + fused concat --------
__global__ __launch_bounds__(256) void out_kernel(
    const float* __restrict__ qkv_cls, const float* __restrict__ qkvn_cls,
    const float* __restrict__ qkv_reg, const float* __restrict__ qkvn_reg,
    const float* __restrict__ cls_score,
    const unsigned* __restrict__ objbits,
    const float* __restrict__ Dcpart, const float* __restrict__ Drpart,
    const float* __restrict__ x_cls, const float* __restrict__ x_reg,
    float* __restrict__ out_cls, float* __restrict__ out_reg)
{
    const int idx = blockIdx.x * 256 + threadIdx.x;  // 12288 = NT*8
    const int i = idx >> 3, h = idx & 7;
    float qn[32], qrn[8];
    #pragma unroll
    for (int d4 = 0; d4 < 8; d4++) {
        float4 v = *(const float4*)&qkvn_cls[i * 768 + h * 32 + d4 * 4];
        qn[d4 * 4 + 0] = v.x; qn[d4 * 4 + 1] = v.y; qn[d4 * 4 + 2] = v.z; qn[d4 * 4 + 3] = v.w;
    }
    #pragma unroll
    for (int d4 = 0; d4 < 2; d4++) {
        float4 v = *(const float4*)&qkvn_reg[i * 192 + h * 8 + d4 * 4];
        qrn[d4 * 4 + 0] = v.x; qrn[d4 * 4 + 1] = v.y; qrn[d4 * 4 + 2] = v.z; qrn[d4 * 4 + 3] = v.w;
    }
    float acc1[32] = {}, acc2[32] = {}, ar1[8] = {}, ar2[8] = {};
    int cnt = 0;
    for (int w = 0; w < 48; w++) {
        unsigned bits = objbits[i * 48 + w];
        cnt += __popc(bits);
        while (bits) {
            const int b = __ffs(bits) - 1;
            bits &= bits - 1u;
            const int j = w * 32 + b;
            float kv[32], vv[32], krv[8], vrv[8];
            #pragma unroll
            for (int d4 = 0; d4 < 8; d4++) {
                float4 kk = *(const float4*)&qkvn_cls[j * 768 + 256 + h * 32 + d4 * 4];
                float4 v4 = *(const float4*)&qkv_cls [j * 768 + 512 + h * 32 + d4 * 4];
                kv[d4 * 4 + 0] = kk.x; kv[d4 * 4 + 1] = kk.y; kv[d4 * 4 + 2] = kk.z; kv[d4 * 4 + 3] = kk.w;
                vv[d4 * 4 + 0] = v4.x; vv[d4 * 4 + 1] = v4.y; vv[d4 * 4 + 2] = v4.z; vv[d4 * 4 + 3] = v4.w;
            }
            #pragma unroll
            for (int d4 = 0; d4 < 2; d4++) {
                float4 kk = *(const float4*)&qkvn_reg[j * 192 + 64  + h * 8 + d4 * 4];
                float4 v4 = *(const float4*)&qkv_reg [j * 192 + 128 + h * 8 + d4 * 4];
                krv[d4 * 4 + 0] = kk.x; krv[d4 * 4 + 1] = kk.y; krv[d4 * 4 + 2] = kk.z; krv[d4 * 4 + 3] = kk.w;
                vrv[d4 * 4 + 0] = v4.x; vrv[d4 * 4 + 1] = v4.y; vrv[d4 * 4 + 2] = v4.z; vrv[d4 * 4 + 3] = v4.w;
            }
            float dotc = 0.f, dotr = 0.f;
            #pragma unroll
            for (int d = 0; d < 32; d++) dotc += qn[d] * kv[d];
            #pragma unroll
            for (int d = 0; d < 8; d++) dotr += qrn[d] * krv[d];
            const float ec = __expf(dotc * SCALE * cls_score[j]);  // obj => cls_mask==1
            const float er = __expf(dotr * SCALE);
            #pragma unroll
            for (int d = 0; d < 32; d++) { acc1[d] += ec * vv[d]; acc2[d] += er * vv[d]; }
            #pragma unroll
            for (int d = 0; d < 8; d++)  { ar1[d] += ec * vrv[d]; ar2[d] += er * vrv[d]; }
        }
    }
    // fused denominator reduce (same summation order as the old denom_reduce)
    float Dcv = 0.f, Drv = 0.f;
    #pragma unroll
    for (int jt = 0; jt < 4; jt++) {
        Dcv += Dcpart[jt * (NT * 8) + idx];
        Drv += Drpart[jt * (NT * 8) + idx];
    }
    const float iDc = 1.0f / Dcv, iDr = 1.0f / Drv;
    const float half_inv = 0.5f / (float)cnt;
    #pragma unroll
    for (int d4 = 0; d4 < 8; d4++) {
        float4 o;
        o.x = (acc1[d4 * 4 + 0] * iDc + acc2[d4 * 4 + 0] * iDr) * half_inv;
        o.y = (acc1[d4 * 4 + 1] * iDc + acc2[d4 * 4 + 1] * iDr) * half_inv;
        o.z = (acc1[d4 * 4 + 2] * iDc + acc2[d4 * 4 + 2] * iDr) * half_inv;
        o.w = (acc1[d4 * 4 + 3] * iDc + acc2[d4 * 4 + 3] * iDr) * half_inv;
        *(float4*)&out_cls[i * 512 + h * 32 + d4 * 4] = o;
    }
    #pragma unroll
    for (int d4 = 0; d4 < 2; d4++) {
        float4 o;
        o.x = (ar1[d4 * 4 + 0] * iDc + ar2[d4 * 4 + 0] * iDr) * half_inv;
        o.y = (ar1[d4 * 4 + 1] * iDc + ar2[d4 * 4 + 1] * iDr) * half_inv;
        o.z = (ar1[d4 * 4 + 2] * iDc + ar2[d4 * 4 + 2] * iDr) * half_inv;
        o.w = (ar1[d4 * 4 + 3] * iDc + ar2[d4 * 4 + 3] * iDr) * half_inv;
        *(float4*)&out_reg[i * 128 + h * 8 + d4 * 4] = o;
    }
    // fused concat copies: x_cls[i, h*32..], x_reg[i, h*8..]
    #pragma unroll
    for (int d4 = 0; d4 < 8; d4++)
        *(float4*)&out_cls[i * 512 + 256 + h * 32 + d4 * 4] =
            *(const float4*)&x_cls[i * 256 + h * 32 + d4 * 4];
    #pragma unroll
    for (int d4 = 0; d4 < 2; d4++)
        *(float4*)&out_reg[i * 128 + 64 + h * 8 + d4 * 4] =
            *(const float4*)&x_reg[i * 64 + h * 8 + d4 * 4];
}

// --------------- expand bit matrices into 8 head copies ---------------------
__global__ __launch_bounds__(256) void expand_kernel(
    const unsigned* __restrict__ simbits, const unsigned* __restrict__ objbits,
    const int* __restrict__ objcnt,
    float* __restrict__ sim_out, float* __restrict__ obj_out)
{
    const int idx = blockIdx.x * 256 + threadIdx.x;  // NT*384
    const int i = idx / 384;
    const int j0 = (idx - i * 384) * 4;
    const unsigned sw = simbits[i * 48 + (j0 >> 5)] >> (j0 & 31);
    const unsigned ow = objbits[i * 48 + (j0 >> 5)] >> (j0 & 31);
    const float inv = 1.0f / (float)objcnt[i];
    float4 sv, ov;
    sv.x = (sw & 1u) ? 1.f : 0.f;  ov.x = (ow & 1u) ? inv : 0.f;
    sv.y = (sw & 2u) ? 1.f : 0.f;  ov.y = (ow & 2u) ? inv : 0.f;
    sv.z = (sw & 4u) ? 1.f : 0.f;  ov.z = (ow & 4u) ? inv : 0.f;
    sv.w = (sw & 8u) ? 1.f : 0.f;  ov.w = (ow & 8u) ? inv : 0.f;
    const int base = i * NT + j0;
    #pragma unroll
    for (int h = 0; h < 8; h++) {
        *(float4*)&sim_out[h * (NT * NT) + base] = sv;
        *(float4*)&obj_out[h * (NT * NT) + base] = ov;
    }
}

extern "C" void kernel_launch(void* const* d_in, const int* in_sizes, int n_in,
                              void* d_out, int out_size, void* d_ws, size_t ws_size,
                              hipStream_t stream)
{
    (void)in_sizes; (void)n_in; (void)out_size; (void)ws_size;
    const float* x_cls     = (const float*)d_in[0];
    const float* x_reg     = (const float*)d_in[1];
    const float* cls_score = (const float*)d_in[2];
    const float* fg_score  = (const float*)d_in[3];
    const float* W_cls     = (const float*)d_in[4];
    const float* W_reg     = (const float*)d_in[5];

    float* out = (float*)d_out;
    float* out_cls = out;                  // 786432 floats
    float* out_reg = out + 786432;         // 196608 floats
    float* sim_out = out + 983040;         // 18874368 floats
    float* obj_out = out + 19857408;       // 18874368 floats

    // Large scratch inside output regions that are only written later
    // (stream-ordered: all reads of these complete before expand_kernel writes):
    float* qkv_cls  = sim_out;             // 1,179,648 floats
    float* qkvn_cls = sim_out + 1179648;   // 1,179,648
    float* qkv_reg  = sim_out + 2359296;   //   294,912
    float* qkvn_reg = sim_out + 2654208;   //   294,912
    float* Dcpart   = obj_out;             //    49,152 (4*1536*8)
    float* Drpart   = obj_out + 49152;     //    49,152 (obj_out written only by expand)

    // Small scratch in d_ws (~0.6 MB)
    char* ws = (char*)d_ws;
    unsigned* simbits = (unsigned*)ws;             // 73728 words
    unsigned* objbits = simbits + 73728;           // 73728 words
    int*      objcnt  = (int*)(objbits + 73728);   // 1536

    gemm_f32<<<dim3(12, 24), 256, 0, stream>>>(x_cls, W_cls, qkv_cls, NT, 256, 768);
    gemm_f32<<<dim3(3, 24), 256, 0, stream>>>(x_reg, W_reg, qkv_reg, NT, 64, 192);
    normalize_k<<<NT, 256, 0, stream>>>(qkv_cls, qkvn_cls, 768, 32);
    normalize_k<<<NT, 256, 0, stream>>>(qkv_reg, qkvn_reg, 192, 8);
    bits_v2<<<dim3(24, 24), 256, 0, stream>>>(qkvn_cls, qkvn_reg, cls_score, fg_score,
                                              simbits, objbits);
    count_kernel<<<6, 256, 0, stream>>>(objbits, objcnt);
    denom_v2<<<dim3(24, 8, 4), 256, 0, stream>>>(qkvn_cls, qkvn_reg, cls_score, Dcpart, Drpart);
    out_kernel<<<48, 256, 0, stream>>>(qkv_cls, qkvn_cls, qkv_reg, qkvn_reg, cls_score,
                                       objbits, Dcpart, Drpart, x_cls, x_reg,
                                       out_cls, out_reg);
    expand_kernel<<<2304, 256, 0, stream>>>(simbits, objbits, objcnt, sim_out, obj_out);
}

// Round 5
// 102.831 us; speedup vs baseline: 2.6533x; 1.4611x over previous
//
#include <hip/hip_runtime.h>
#include <hip/hip_bf16.h>

#define NT 1536
#define SCALE 0.17677669529663687f  // (256/8)^-0.5

typedef __attribute__((ext_vector_type(8))) short bf16x8;
typedef __attribute__((ext_vector_type(4))) float f32x4;

static __device__ __forceinline__ unsigned short f2b(float x) {
    __hip_bfloat16 h = __float2bfloat16(x);
    union { __hip_bfloat16 b; unsigned short u; } cv; cv.b = h; return cv.u;
}

// ------ GEMM + fused per-head L2 normalize + bf16 emit ----------------------
// C[M,NN] = A[M,K] @ B[K,NN]; head groups of (glanes*4) cols normalized.
__global__ __launch_bounds__(256) void gemm_norm(const float* __restrict__ A,
    const float* __restrict__ B, float* __restrict__ qkv, float* __restrict__ qkvn,
    unsigned short* __restrict__ qkvnb, int K, int NN, int glanes)
{
    __shared__ float As[16][68];
    __shared__ float Bs[16][68];
    const int t = threadIdx.x;
    const int tx = t & 15, ty = t >> 4;
    const int i0 = blockIdx.y * 64, j0 = blockIdx.x * 64;
    float acc[4][4] = {};
    for (int k0 = 0; k0 < K; k0 += 16) {
        float4 av = *(const float4*)&A[(i0 + (t >> 2)) * K + k0 + (t & 3) * 4];
        float4 bv = *(const float4*)&B[(k0 + (t >> 4)) * NN + j0 + tx * 4];
        __syncthreads();
        As[(t & 3) * 4 + 0][t >> 2] = av.x;
        As[(t & 3) * 4 + 1][t >> 2] = av.y;
        As[(t & 3) * 4 + 2][t >> 2] = av.z;
        As[(t & 3) * 4 + 3][t >> 2] = av.w;
        *(float4*)&Bs[t >> 4][tx * 4] = bv;
        __syncthreads();
        #pragma unroll
        for (int kk = 0; kk < 16; kk++) {
            float4 a = *(const float4*)&As[kk][ty * 4];
            float4 b = *(const float4*)&Bs[kk][tx * 4];
            float ar_[4] = {a.x, a.y, a.z, a.w};
            float br_[4] = {b.x, b.y, b.z, b.w};
            #pragma unroll
            for (int r = 0; r < 4; r++)
                #pragma unroll
                for (int c = 0; c < 4; c++)
                    acc[r][c] += ar_[r] * br_[c];
        }
    }
    #pragma unroll
    for (int r = 0; r < 4; r++) {
        const int row = i0 + ty * 4 + r, col = j0 + tx * 4;
        float4 o = {acc[r][0], acc[r][1], acc[r][2], acc[r][3]};
        *(float4*)&qkv[row * NN + col] = o;
        float s = o.x * o.x + o.y * o.y + o.z * o.z + o.w * o.w;
        for (int m = 1; m < glanes; m <<= 1) s += __shfl_xor(s, m);
        const float inv = 1.0f / sqrtf(s);
        float4 n = {o.x * inv, o.y * inv, o.z * inv, o.w * inv};
        *(float4*)&qkvn[row * NN + col] = n;
        ushort4 nb;
        nb.x = f2b(n.x); nb.y = f2b(n.y); nb.z = f2b(n.z); nb.w = f2b(n.w);
        *(ushort4*)&qkvnb[row * NN + col] = nb;
    }
}

// ------ sim/obj bit matrices via MFMA bf16 ----------------------------------
__global__ __launch_bounds__(256) void bits_mfma(
    const unsigned short* __restrict__ qkvnb_cls, const unsigned short* __restrict__ qkvnb_reg,
    const float* __restrict__ cls_score, const float* __restrict__ fg_score,
    unsigned* __restrict__ simbits, unsigned* __restrict__ objbits)
{
    __shared__ short Ai[64 * 40], Bj[64 * 40];     // 80B row pitch (2-way banks = free)
    __shared__ float csi[64], csj[64], fgi[64], fgj[64];
    __shared__ unsigned simw[64][2], objw[64][2];
    const int t = threadIdx.x;
    const int lane = t & 63;
    const int wv = t >> 6, wr = wv >> 1, wc = wv & 1;   // wr: i-stripe, wc: j-stripe
    const int i0 = blockIdx.y * 64, j0 = blockIdx.x * 64;
    if (t < 64)       { csi[t] = cls_score[i0 + t]; fgi[t] = fg_score[i0 + t]; }
    else if (t < 128) { csj[t - 64] = cls_score[j0 + t - 64]; fgj[t - 64] = fg_score[j0 + t - 64]; }
    const int sr = t >> 2, sc = t & 3;
    f32x4 ac[2][2], ar[2][2];
    #pragma unroll
    for (int a = 0; a < 2; a++)
        #pragma unroll
        for (int b = 0; b < 2; b++) { ac[a][b] = (f32x4){0,0,0,0}; ar[a][b] = (f32x4){0,0,0,0}; }
    // cls vn (K=256): 8 K-steps of 32
    for (int ks = 0; ks < 8; ks++) {
        __syncthreads();
        *(float4*)&Ai[sr * 40 + sc * 8] = *(const float4*)&qkvnb_cls[(i0 + sr) * 768 + 512 + ks * 32 + sc * 8];
        *(float4*)&Bj[sr * 40 + sc * 8] = *(const float4*)&qkvnb_cls[(j0 + sr) * 768 + 512 + ks * 32 + sc * 8];
        __syncthreads();
        const int k8 = (lane >> 4) * 8;
        bf16x8 af[2], bf_[2];
        #pragma unroll
        for (int fr = 0; fr < 2; fr++)
            af[fr] = *(const bf16x8*)&Ai[(wr * 32 + fr * 16 + (lane & 15)) * 40 + k8];
        #pragma unroll
        for (int fc = 0; fc < 2; fc++)
            bf_[fc] = *(const bf16x8*)&Bj[(wc * 32 + fc * 16 + (lane & 15)) * 40 + k8];
        #pragma unroll
        for (int fr = 0; fr < 2; fr++)
            #pragma unroll
            for (int fc = 0; fc < 2; fc++)
                ac[fr][fc] = __builtin_amdgcn_mfma_f32_16x16x32_bf16(af[fr], bf_[fc], ac[fr][fc], 0, 0, 0);
    }
    // reg vrn (K=64): 2 K-steps
    for (int ks = 0; ks < 2; ks++) {
        __syncthreads();
        *(float4*)&Ai[sr * 40 + sc * 8] = *(const float4*)&qkvnb_reg[(i0 + sr) * 192 + 128 + ks * 32 + sc * 8];
        *(float4*)&Bj[sr * 40 + sc * 8] = *(const float4*)&qkvnb_reg[(j0 + sr) * 192 + 128 + ks * 32 + sc * 8];
        __syncthreads();
        const int k8 = (lane >> 4) * 8;
        bf16x8 af[2], bf_[2];
        #pragma unroll
        for (int fr = 0; fr < 2; fr++)
            af[fr] = *(const bf16x8*)&Ai[(wr * 32 + fr * 16 + (lane & 15)) * 40 + k8];
        #pragma unroll
        for (int fc = 0; fc < 2; fc++)
            bf_[fc] = *(const bf16x8*)&Bj[(wc * 32 + fc * 16 + (lane & 15)) * 40 + k8];
        #pragma unroll
        for (int fr = 0; fr < 2; fr++)
            #pragma unroll
            for (int fc = 0; fc < 2; fc++)
                ar[fr][fc] = __builtin_amdgcn_mfma_f32_16x16x32_bf16(af[fr], bf_[fc], ar[fr][fc], 0, 0, 0);
    }
    // epilogue: thresholds + ballots (C row = i = (lane>>4)*4+reg, col = j = lane&15)
    #pragma unroll
    for (int fr = 0; fr < 2; fr++)
        #pragma unroll
        for (int r4 = 0; r4 < 4; r4++) {
            const int rloc = wr * 32 + fr * 16 + (lane >> 4) * 4 + r4;
            const float ci = csi[rloc] - 0.1f, fgv = fgi[rloc] - 0.1f;
            unsigned sm[2], om[2];
            #pragma unroll
            for (int fc = 0; fc < 2; fc++) {
                const int cloc = wc * 32 + fc * 16 + (lane & 15);
                const bool clsb = csj[cloc] > ci;
                const bool fgb  = fgj[cloc] > fgv;
                const bool sim = (ac[fr][fc][r4] * 0.125f > 0.75f) && clsb && fgb;
                const bool obj = sim && (ar[fr][fc][r4] * 0.125f > 0.75f);
                unsigned long long bs = __ballot(sim);
                unsigned long long bo = __ballot(obj);
                const int g = lane >> 4;
                sm[fc] = (unsigned)((bs >> (16 * g)) & 0xFFFFull);
                om[fc] = (unsigned)((bo >> (16 * g)) & 0xFFFFull);
            }
            if ((lane & 15) == 0) {
                simw[rloc][wc] = sm[0] | (sm[1] << 16);
                objw[rloc][wc] = om[0] | (om[1] << 16);
            }
        }
    __syncthreads();
    if (t < 128) {
        const int row = t >> 1, w = t & 1;
        simbits[(i0 + row) * 48 + blockIdx.x * 2 + w] = simw[row][w];
        objbits[(i0 + row) * 48 + blockIdx.x * 2 + w] = objw[row][w];
    }
}

// ------ per-row obj counts ---------------------------------------------------
__global__ __launch_bounds__(256) void count_kernel(
    const unsigned* __restrict__ objbits, int* __restrict__ objcnt)
{
    const int i = blockIdx.x * 256 + threadIdx.x;  // 1536
    int c = 0;
    #pragma unroll 8
    for (int w = 0; w < 48; w++) c += __popc(objbits[i * 48 + w]);
    objcnt[i] = c;
}

// ------ softmax denominators via MFMA bf16 (C rows = j, cols = i) -----------
__global__ __launch_bounds__(256) void denom_mfma(
    const unsigned short* __restrict__ qkvnb_cls, const unsigned short* __restrict__ qkvnb_reg,
    const float* __restrict__ cls_score,
    float* __restrict__ Dcpart, float* __restrict__ Drpart)
{
    __shared__ short Ah[64 * 40], Bh[64 * 40];   // per-head K(j) rows / Q(i) rows
    __shared__ short Kr[64 * 72], Qr[64 * 72];   // reg full-K (64 bf16, 144B pitch)
    __shared__ float csi[64], csj[64];
    const int t = threadIdx.x;
    const int lane = t & 63;
    const int wv = t >> 6, wr = wv >> 1, wc = wv & 1;   // wr: j-stripe, wc: i-stripe
    const int i0 = blockIdx.y * 64, j0 = blockIdx.x * 64;
    #pragma unroll
    for (int it = 0; it < 2; it++) {
        const int u = it * 256 + t;
        const int r = u >> 3, c = u & 7;
        *(float4*)&Kr[r * 72 + c * 8] = *(const float4*)&qkvnb_reg[(j0 + r) * 192 + 64 + c * 8];
        *(float4*)&Qr[r * 72 + c * 8] = *(const float4*)&qkvnb_reg[(i0 + r) * 192 + 0 + c * 8];
    }
    if (t < 64)       csj[t] = cls_score[j0 + t];
    else if (t < 128) csi[t - 64] = cls_score[i0 + t - 64];
    __syncthreads();
    float cI[2], cJ[8];
    #pragma unroll
    for (int fc = 0; fc < 2; fc++) cI[fc] = csi[wc * 32 + fc * 16 + (lane & 15)] - 0.1f;
    #pragma unroll
    for (int fr = 0; fr < 2; fr++)
        #pragma unroll
        for (int r4 = 0; r4 < 4; r4++)
            cJ[fr * 4 + r4] = csj[wr * 32 + fr * 16 + (lane >> 4) * 4 + r4];
    float pC[2][8], pR[2][8];
    #pragma unroll
    for (int fc = 0; fc < 2; fc++)
        #pragma unroll
        for (int h = 0; h < 8; h++) { pC[fc][h] = 0.f; pR[fc][h] = 0.f; }
    const int sr = t >> 2, sc = t & 3;
    const bool g0 = (lane >> 4) == 0;
    const bf16x8 zz = {0, 0, 0, 0, 0, 0, 0, 0};
    for (int h = 0; h < 8; h++) {
        __syncthreads();
        *(float4*)&Ah[sr * 40 + sc * 8] = *(const float4*)&qkvnb_cls[(j0 + sr) * 768 + 256 + h * 32 + sc * 8];
        *(float4*)&Bh[sr * 40 + sc * 8] = *(const float4*)&qkvnb_cls[(i0 + sr) * 768 + 0   + h * 32 + sc * 8];
        __syncthreads();
        const int k8 = (lane >> 4) * 8;
        bf16x8 a[2], b[2], arg[2], brg[2];
        #pragma unroll
        for (int fr = 0; fr < 2; fr++) {
            const int row = wr * 32 + fr * 16 + (lane & 15);
            a[fr] = *(const bf16x8*)&Ah[row * 40 + k8];
            arg[fr] = g0 ? *(const bf16x8*)&Kr[row * 72 + h * 8] : zz;
        }
        #pragma unroll
        for (int fc = 0; fc < 2; fc++) {
            const int row = wc * 32 + fc * 16 + (lane & 15);
            b[fc] = *(const bf16x8*)&Bh[row * 40 + k8];
            brg[fc] = g0 ? *(const bf16x8*)&Qr[row * 72 + h * 8] : zz;
        }
        f32x4 acc[2][2], racc[2][2];
        #pragma unroll
        for (int fr = 0; fr < 2; fr++)
            #pragma unroll
            for (int fc = 0; fc < 2; fc++) {
                acc[fr][fc] = (f32x4){0,0,0,0};
                racc[fr][fc] = (f32x4){0,0,0,0};
                acc[fr][fc] = __builtin_amdgcn_mfma_f32_16x16x32_bf16(a[fr], b[fc], acc[fr][fc], 0, 0, 0);
                racc[fr][fc] = __builtin_amdgcn_mfma_f32_16x16x32_bf16(arg[fr], brg[fc], racc[fr][fc], 0, 0, 0);
            }
        #pragma unroll
        for (int fc = 0; fc < 2; fc++) {
            float sC = 0.f, sR = 0.f;
            #pragma unroll
            for (int fr = 0; fr < 2; fr++)
                #pragma unroll
                for (int r4 = 0; r4 < 4; r4++) {
                    const float cj = cJ[fr * 4 + r4];
                    const float lc = (cj > cI[fc]) ? acc[fr][fc][r4] * SCALE * cj : 0.0f;
                    sC += __expf(lc);
                    sR += __expf(racc[fr][fc][r4] * SCALE);
                }
            pC[fc][h] += sC; pR[fc][h] += sR;
        }
    }
    // reduce over the 4 j-subgroups (lane>>4), write per-wave partials
    #pragma unroll
    for (int fc = 0; fc < 2; fc++)
        #pragma unroll
        for (int h = 0; h < 8; h++) {
            float v = pC[fc][h]; v += __shfl_xor(v, 16); v += __shfl_xor(v, 32);
            float u = pR[fc][h]; u += __shfl_xor(u, 16); u += __shfl_xor(u, 32);
            if (lane < 16) {
                const int i = i0 + wc * 32 + fc * 16 + lane;
                const int p = blockIdx.x * 2 + wr;
                Dcpart[(p * NT + i) * 8 + h] = v;
                Drpart[(p * NT + i) * 8 + h] = u;
            }
        }
}

// ------ sparse attn @ v, 8-way j-split, fused denom-reduce + concat ---------
__global__ __launch_bounds__(256) void out_kernel(
    const float* __restrict__ qkv_cls, const float* __restrict__ qkvn_cls,
    const float* __restrict__ qkv_reg, const float* __restrict__ qkvn_reg,
    const float* __restrict__ cls_score,
    const unsigned* __restrict__ objbits,
    const float* __restrict__ Dcpart, const float* __restrict__ Drpart,
    const float* __restrict__ x_cls, const float* __restrict__ x_reg,
    float* __restrict__ out_cls, float* __restrict__ out_reg)
{
    const int idx = blockIdx.x * 256 + threadIdx.x;  // 98304 = NT*8*8
    const int i = idx >> 6, h = (idx >> 3) & 7, s = idx & 7;
    float qn[32], qrn[8];
    #pragma unroll
    for (int d4 = 0; d4 < 8; d4++) {
        float4 v = *(const float4*)&qkvn_cls[i * 768 + h * 32 + d4 * 4];
        qn[d4 * 4 + 0] = v.x; qn[d4 * 4 + 1] = v.y; qn[d4 * 4 + 2] = v.z; qn[d4 * 4 + 3] = v.w;
    }
    #pragma unroll
    for (int d4 = 0; d4 < 2; d4++) {
        float4 v = *(const float4*)&qkvn_reg[i * 192 + h * 8 + d4 * 4];
        qrn[d4 * 4 + 0] = v.x; qrn[d4 * 4 + 1] = v.y; qrn[d4 * 4 + 2] = v.z; qrn[d4 * 4 + 3] = v.w;
    }
    float acc1[32] = {}, acc2[32] = {}, ar1[8] = {}, ar2[8] = {};
    int cnt = 0;
    for (int w = s * 6; w < s * 6 + 6; w++) {
        unsigned bits = objbits[i * 48 + w];
        cnt += __popc(bits);
        while (bits) {
            const int b = __ffs(bits) - 1;
            bits &= bits - 1u;
            const int j = w * 32 + b;
            float kv[32], vv[32], krv[8], vrv[8];
            #pragma unroll
            for (int d4 = 0; d4 < 8; d4++) {
                float4 kk = *(const float4*)&qkvn_cls[j * 768 + 256 + h * 32 + d4 * 4];
                float4 v4 = *(const float4*)&qkv_cls [j * 768 + 512 + h * 32 + d4 * 4];
                kv[d4 * 4 + 0] = kk.x; kv[d4 * 4 + 1] = kk.y; kv[d4 * 4 + 2] = kk.z; kv[d4 * 4 + 3] = kk.w;
                vv[d4 * 4 + 0] = v4.x; vv[d4 * 4 + 1] = v4.y; vv[d4 * 4 + 2] = v4.z; vv[d4 * 4 + 3] = v4.w;
            }
            #pragma unroll
            for (int d4 = 0; d4 < 2; d4++) {
                float4 kk = *(const float4*)&qkvn_reg[j * 192 + 64  + h * 8 + d4 * 4];
                float4 v4 = *(const float4*)&qkv_reg [j * 192 + 128 + h * 8 + d4 * 4];
                krv[d4 * 4 + 0] = kk.x; krv[d4 * 4 + 1] = kk.y; krv[d4 * 4 + 2] = kk.z; krv[d4 * 4 + 3] = kk.w;
                vrv[d4 * 4 + 0] = v4.x; vrv[d4 * 4 + 1] = v4.y; vrv[d4 * 4 + 2] = v4.z; vrv[d4 * 4 + 3] = v4.w;
            }
            float dotc = 0.f, dotr = 0.f;
            #pragma unroll
            for (int d = 0; d < 32; d++) dotc += qn[d] * kv[d];
            #pragma unroll
            for (int d = 0; d < 8; d++) dotr += qrn[d] * krv[d];
            const float ec = __expf(dotc * SCALE * cls_score[j]);
            const float er = __expf(dotr * SCALE);
            #pragma unroll
            for (int d = 0; d < 32; d++) { acc1[d] += ec * vv[d]; acc2[d] += er * vv[d]; }
            #pragma unroll
            for (int d = 0; d < 8; d++)  { ar1[d] += ec * vrv[d]; ar2[d] += er * vrv[d]; }
        }
    }
    // partial denominator sums (6 of 48 per thread)
    float Dcv = 0.f, Drv = 0.f;
    for (int p = s * 6; p < s * 6 + 6; p++) {
        Dcv += Dcpart[p * (NT * 8) + i * 8 + h];
        Drv += Drpart[p * (NT * 8) + i * 8 + h];
    }
    // combine the 8 j-splits (lanes s = lane&7)
    #pragma unroll
    for (int m = 1; m < 8; m <<= 1) {
        #pragma unroll
        for (int d = 0; d < 32; d++) { acc1[d] += __shfl_xor(acc1[d], m); acc2[d] += __shfl_xor(acc2[d], m); }
        #pragma unroll
        for (int d = 0; d < 8; d++)  { ar1[d] += __shfl_xor(ar1[d], m);  ar2[d] += __shfl_xor(ar2[d], m); }
        cnt += __shfl_xor(cnt, m);
        Dcv += __shfl_xor(Dcv, m);
        Drv += __shfl_xor(Drv, m);
    }
    if (s == 0) {
        const float iDc = 1.0f / Dcv, iDr = 1.0f / Drv;
        const float half_inv = 0.5f / (float)cnt;
        #pragma unroll
        for (int d4 = 0; d4 < 8; d4++) {
            float4 o;
            o.x = (acc1[d4 * 4 + 0] * iDc + acc2[d4 * 4 + 0] * iDr) * half_inv;
            o.y = (acc1[d4 * 4 + 1] * iDc + acc2[d4 * 4 + 1] * iDr) * half_inv;
            o.z = (acc1[d4 * 4 + 2] * iDc + acc2[d4 * 4 + 2] * iDr) * half_inv;
            o.w = (acc1[d4 * 4 + 3] * iDc + acc2[d4 * 4 + 3] * iDr) * half_inv;
            *(float4*)&out_cls[i * 512 + h * 32 + d4 * 4] = o;
        }
        #pragma unroll
        for (int d4 = 0; d4 < 2; d4++) {
            float4 o;
            o.x = (ar1[d4 * 4 + 0] * iDc + ar2[d4 * 4 + 0] * iDr) * half_inv;
            o.y = (ar1[d4 * 4 + 1] * iDc + ar2[d4 * 4 + 1] * iDr) * half_inv;
            o.z = (ar1[d4 * 4 + 2] * iDc + ar2[d4 * 4 + 2] * iDr) * half_inv;
            o.w = (ar1[d4 * 4 + 3] * iDc + ar2[d4 * 4 + 3] * iDr) * half_inv;
            *(float4*)&out_reg[i * 128 + h * 8 + d4 * 4] = o;
        }
        #pragma unroll
        for (int d4 = 0; d4 < 8; d4++)
            *(float4*)&out_cls[i * 512 + 256 + h * 32 + d4 * 4] =
                *(const float4*)&x_cls[i * 256 + h * 32 + d4 * 4];
        #pragma unroll
        for (int d4 = 0; d4 < 2; d4++)
            *(float4*)&out_reg[i * 128 + 64 + h * 8 + d4 * 4] =
                *(const float4*)&x_reg[i * 64 + h * 8 + d4 * 4];
    }
}

// ------ expand bit matrices into 8 head copies ------------------------------
__global__ __launch_bounds__(256) void expand_kernel(
    const unsigned* __restrict__ simbits, const unsigned* __restrict__ objbits,
    const int* __restrict__ objcnt,
    float* __restrict__ sim_out, float* __restrict__ obj_out)
{
    const int idx = blockIdx.x * 256 + threadIdx.x;  // NT*384
    const int i = idx / 384;
    const int j0 = (idx - i * 384) * 4;
    const unsigned sw = simbits[i * 48 + (j0 >> 5)] >> (j0 & 31);
    const unsigned ow = objbits[i * 48 + (j0 >> 5)] >> (j0 & 31);
    const float inv = 1.0f / (float)objcnt[i];
    float4 sv, ov;
    sv.x = (sw & 1u) ? 1.f : 0.f;  ov.x = (ow & 1u) ? inv : 0.f;
    sv.y = (sw & 2u) ? 1.f : 0.f;  ov.y = (ow & 2u) ? inv : 0.f;
    sv.z = (sw & 4u) ? 1.f : 0.f;  ov.z = (ow & 4u) ? inv : 0.f;
    sv.w = (sw & 8u) ? 1.f : 0.f;  ov.w = (ow & 8u) ? inv : 0.f;
    const int base = i * NT + j0;
    #pragma unroll
    for (int h = 0; h < 8; h++) {
        *(float4*)&sim_out[h * (NT * NT) + base] = sv;
        *(float4*)&obj_out[h * (NT * NT) + base] = ov;
    }
}

extern "C" void kernel_launch(void* const* d_in, const int* in_sizes, int n_in,
                              void* d_out, int out_size, void* d_ws, size_t ws_size,
                              hipStream_t stream)
{
    (void)in_sizes; (void)n_in; (void)out_size; (void)ws_size;
    const float* x_cls     = (const float*)d_in[0];
    const float* x_reg     = (const float*)d_in[1];
    const float* cls_score = (const float*)d_in[2];
    const float* fg_score  = (const float*)d_in[3];
    const float* W_cls     = (const float*)d_in[4];
    const float* W_reg     = (const float*)d_in[5];

    float* out = (float*)d_out;
    float* out_cls = out;                  // 786432 floats
    float* out_reg = out + 786432;         // 196608 floats
    float* sim_out = out + 983040;         // 18874368 floats
    float* obj_out = out + 19857408;       // 18874368 floats

    // Large scratch inside output regions (all reads complete before
    // expand_kernel overwrites them; stream-ordered):
    float* qkv_cls  = sim_out;                              // 1,179,648
    float* qkvn_cls = sim_out + 1179648;                    // 1,179,648
    float* qkv_reg  = sim_out + 2359296;                    //   294,912
    float* qkvn_reg = sim_out + 2654208;                    //   294,912
    unsigned short* qkvnb_cls = (unsigned short*)(sim_out + 2949120);  // 1,179,648 u16
    unsigned short* qkvnb_reg = (unsigned short*)(sim_out + 3538944);  //   294,912 u16
    float* Dcpart   = obj_out;                              //   589,824 (48*1536*8)
    float* Drpart   = obj_out + 589824;                     //   589,824

    // Small scratch in d_ws (~0.6 MB)
    char* ws = (char*)d_ws;
    unsigned* simbits = (unsigned*)ws;             // 73728 words
    unsigned* objbits = simbits + 73728;           // 73728 words
    int*      objcnt  = (int*)(objbits + 73728);   // 1536

    gemm_norm<<<dim3(12, 24), 256, 0, stream>>>(x_cls, W_cls, qkv_cls, qkvn_cls, qkvnb_cls, 256, 768, 8);
    gemm_norm<<<dim3(3, 24), 256, 0, stream>>>(x_reg, W_reg, qkv_reg, qkvn_reg, qkvnb_reg, 64, 192, 2);
    bits_mfma<<<dim3(24, 24), 256, 0, stream>>>(qkvnb_cls, qkvnb_reg, cls_score, fg_score,
                                                simbits, objbits);
    count_kernel<<<6, 256, 0, stream>>>(objbits, objcnt);
    denom_mfma<<<dim3(24, 24), 256, 0, stream>>>(qkvnb_cls, qkvnb_reg, cls_score, Dcpart, Drpart);
    out_kernel<<<384, 256, 0, stream>>>(qkv_cls, qkvn_cls, qkv_reg, qkvn_reg, cls_score,
                                        objbits, Dcpart, Drpart, x_cls, x_reg,
                                        out_cls, out_reg);
    expand_kernel<<<2304, 256, 0, stream>>>(simbits, objbits, objcnt, sim_out, obj_out);
}

// Round 6
// 96.863 us; speedup vs baseline: 2.8168x; 1.0616x over previous
//
#include <hip/hip_runtime.h>
#include <hip/hip_bf16.h>

#define NT 1536
#define SCALE 0.17677669529663687f  // (256/8)^-0.5

typedef __attribute__((ext_vector_type(8))) short bf16x8;
typedef __attribute__((ext_vector_type(4))) float f32x4;

static __device__ __forceinline__ unsigned short f2b(float x) {
    __hip_bfloat16 h = __float2bfloat16(x);
    union { __hip_bfloat16 b; unsigned short u; } cv; cv.b = h; return cv.u;
}

// ------ GEMM + fused per-head L2 normalize + bf16 emit ----------------------
__global__ __launch_bounds__(256) void gemm_norm(const float* __restrict__ A,
    const float* __restrict__ B, float* __restrict__ qkv, float* __restrict__ qkvn,
    unsigned short* __restrict__ qkvnb, int K, int NN, int glanes)
{
    __shared__ float As[16][68];
    __shared__ float Bs[16][68];
    const int t = threadIdx.x;
    const int tx = t & 15, ty = t >> 4;
    const int i0 = blockIdx.y * 64, j0 = blockIdx.x * 64;
    float acc[4][4] = {};
    for (int k0 = 0; k0 < K; k0 += 16) {
        float4 av = *(const float4*)&A[(i0 + (t >> 2)) * K + k0 + (t & 3) * 4];
        float4 bv = *(const float4*)&B[(k0 + (t >> 4)) * NN + j0 + tx * 4];
        __syncthreads();
        As[(t & 3) * 4 + 0][t >> 2] = av.x;
        As[(t & 3) * 4 + 1][t >> 2] = av.y;
        As[(t & 3) * 4 + 2][t >> 2] = av.z;
        As[(t & 3) * 4 + 3][t >> 2] = av.w;
        *(float4*)&Bs[t >> 4][tx * 4] = bv;
        __syncthreads();
        #pragma unroll
        for (int kk = 0; kk < 16; kk++) {
            float4 a = *(const float4*)&As[kk][ty * 4];
            float4 b = *(const float4*)&Bs[kk][tx * 4];
            float ar_[4] = {a.x, a.y, a.z, a.w};
            float br_[4] = {b.x, b.y, b.z, b.w};
            #pragma unroll
            for (int r = 0; r < 4; r++)
                #pragma unroll
                for (int c = 0; c < 4; c++)
                    acc[r][c] += ar_[r] * br_[c];
        }
    }
    #pragma unroll
    for (int r = 0; r < 4; r++) {
        const int row = i0 + ty * 4 + r, col = j0 + tx * 4;
        float4 o = {acc[r][0], acc[r][1], acc[r][2], acc[r][3]};
        *(float4*)&qkv[row * NN + col] = o;
        float s = o.x * o.x + o.y * o.y + o.z * o.z + o.w * o.w;
        for (int m = 1; m < glanes; m <<= 1) s += __shfl_xor(s, m);
        const float inv = 1.0f / sqrtf(s);
        float4 n = {o.x * inv, o.y * inv, o.z * inv, o.w * inv};
        *(float4*)&qkvn[row * NN + col] = n;
        ushort4 nb;
        nb.x = f2b(n.x); nb.y = f2b(n.y); nb.z = f2b(n.z); nb.w = f2b(n.w);
        *(ushort4*)&qkvnb[row * NN + col] = nb;
    }
}

// ------ sim/obj bit matrices via MFMA bf16 ----------------------------------
__global__ __launch_bounds__(256) void bits_mfma(
    const unsigned short* __restrict__ qkvnb_cls, const unsigned short* __restrict__ qkvnb_reg,
    const float* __restrict__ cls_score, const float* __restrict__ fg_score,
    unsigned* __restrict__ simbits, unsigned* __restrict__ objbits)
{
    __shared__ short Ai[64 * 40], Bj[64 * 40];     // 80B row pitch (2-way banks = free)
    __shared__ float csi[64], csj[64], fgi[64], fgj[64];
    __shared__ unsigned simw[64][2], objw[64][2];
    const int t = threadIdx.x;
    const int lane = t & 63;
    const int wv = t >> 6, wr = wv >> 1, wc = wv & 1;
    const int i0 = blockIdx.y * 64, j0 = blockIdx.x * 64;
    if (t < 64)       { csi[t] = cls_score[i0 + t]; fgi[t] = fg_score[i0 + t]; }
    else if (t < 128) { csj[t - 64] = cls_score[j0 + t - 64]; fgj[t - 64] = fg_score[j0 + t - 64]; }
    const int sr = t >> 2, sc = t & 3;
    f32x4 ac[2][2], ar[2][2];
    #pragma unroll
    for (int a = 0; a < 2; a++)
        #pragma unroll
        for (int b = 0; b < 2; b++) { ac[a][b] = (f32x4){0,0,0,0}; ar[a][b] = (f32x4){0,0,0,0}; }
    for (int ks = 0; ks < 8; ks++) {
        __syncthreads();
        *(float4*)&Ai[sr * 40 + sc * 8] = *(const float4*)&qkvnb_cls[(i0 + sr) * 768 + 512 + ks * 32 + sc * 8];
        *(float4*)&Bj[sr * 40 + sc * 8] = *(const float4*)&qkvnb_cls[(j0 + sr) * 768 + 512 + ks * 32 + sc * 8];
        __syncthreads();
        const int k8 = (lane >> 4) * 8;
        bf16x8 af[2], bf_[2];
        #pragma unroll
        for (int fr = 0; fr < 2; fr++)
            af[fr] = *(const bf16x8*)&Ai[(wr * 32 + fr * 16 + (lane & 15)) * 40 + k8];
        #pragma unroll
        for (int fc = 0; fc < 2; fc++)
            bf_[fc] = *(const bf16x8*)&Bj[(wc * 32 + fc * 16 + (lane & 15)) * 40 + k8];
        #pragma unroll
        for (int fr = 0; fr < 2; fr++)
            #pragma unroll
            for (int fc = 0; fc < 2; fc++)
                ac[fr][fc] = __builtin_amdgcn_mfma_f32_16x16x32_bf16(af[fr], bf_[fc], ac[fr][fc], 0, 0, 0);
    }
    for (int ks = 0; ks < 2; ks++) {
        __syncthreads();
        *(float4*)&Ai[sr * 40 + sc * 8] = *(const float4*)&qkvnb_reg[(i0 + sr) * 192 + 128 + ks * 32 + sc * 8];
        *(float4*)&Bj[sr * 40 + sc * 8] = *(const float4*)&qkvnb_reg[(j0 + sr) * 192 + 128 + ks * 32 + sc * 8];
        __syncthreads();
        const int k8 = (lane >> 4) * 8;
        bf16x8 af[2], bf_[2];
        #pragma unroll
        for (int fr = 0; fr < 2; fr++)
            af[fr] = *(const bf16x8*)&Ai[(wr * 32 + fr * 16 + (lane & 15)) * 40 + k8];
        #pragma unroll
        for (int fc = 0; fc < 2; fc++)
            bf_[fc] = *(const bf16x8*)&Bj[(wc * 32 + fc * 16 + (lane & 15)) * 40 + k8];
        #pragma unroll
        for (int fr = 0; fr < 2; fr++)
            #pragma unroll
            for (int fc = 0; fc < 2; fc++)
                ar[fr][fc] = __builtin_amdgcn_mfma_f32_16x16x32_bf16(af[fr], bf_[fc], ar[fr][fc], 0, 0, 0);
    }
    #pragma unroll
    for (int fr = 0; fr < 2; fr++)
        #pragma unroll
        for (int r4 = 0; r4 < 4; r4++) {
            const int rloc = wr * 32 + fr * 16 + (lane >> 4) * 4 + r4;
            const float ci = csi[rloc] - 0.1f, fgv = fgi[rloc] - 0.1f;
            unsigned sm[2], om[2];
            #pragma unroll
            for (int fc = 0; fc < 2; fc++) {
                const int cloc = wc * 32 + fc * 16 + (lane & 15);
                const bool clsb = csj[cloc] > ci;
                const bool fgb  = fgj[cloc] > fgv;
                const bool sim = (ac[fr][fc][r4] * 0.125f > 0.75f) && clsb && fgb;
                const bool obj = sim && (ar[fr][fc][r4] * 0.125f > 0.75f);
                unsigned long long bs = __ballot(sim);
                unsigned long long bo = __ballot(obj);
                const int g = lane >> 4;
                sm[fc] = (unsigned)((bs >> (16 * g)) & 0xFFFFull);
                om[fc] = (unsigned)((bo >> (16 * g)) & 0xFFFFull);
            }
            if ((lane & 15) == 0) {
                simw[rloc][wc] = sm[0] | (sm[1] << 16);
                objw[rloc][wc] = om[0] | (om[1] << 16);
            }
        }
    __syncthreads();
    if (t < 128) {
        const int row = t >> 1, w = t & 1;
        simbits[(i0 + row) * 48 + blockIdx.x * 2 + w] = simw[row][w];
        objbits[(i0 + row) * 48 + blockIdx.x * 2 + w] = objw[row][w];
    }
}

// ------ softmax denominators via MFMA bf16 (C rows = j, cols = i) -----------
__global__ __launch_bounds__(256) void denom_mfma(
    const unsigned short* __restrict__ qkvnb_cls, const unsigned short* __restrict__ qkvnb_reg,
    const float* __restrict__ cls_score,
    float* __restrict__ Dcpart, float* __restrict__ Drpart)
{
    __shared__ short Ah[64 * 40], Bh[64 * 40];
    __shared__ short Kr[64 * 72], Qr[64 * 72];
    __shared__ float csi[64], csj[64];
    const int t = threadIdx.x;
    const int lane = t & 63;
    const int wv = t >> 6, wr = wv >> 1, wc = wv & 1;
    const int i0 = blockIdx.y * 64, j0 = blockIdx.x * 64;
    #pragma unroll
    for (int it = 0; it < 2; it++) {
        const int u = it * 256 + t;
        const int r = u >> 3, c = u & 7;
        *(float4*)&Kr[r * 72 + c * 8] = *(const float4*)&qkvnb_reg[(j0 + r) * 192 + 64 + c * 8];
        *(float4*)&Qr[r * 72 + c * 8] = *(const float4*)&qkvnb_reg[(i0 + r) * 192 + 0 + c * 8];
    }
    if (t < 64)       csj[t] = cls_score[j0 + t];
    else if (t < 128) csi[t - 64] = cls_score[i0 + t - 64];
    __syncthreads();
    float cI[2], cJ[8];
    #pragma unroll
    for (int fc = 0; fc < 2; fc++) cI[fc] = csi[wc * 32 + fc * 16 + (lane & 15)] - 0.1f;
    #pragma unroll
    for (int fr = 0; fr < 2; fr++)
        #pragma unroll
        for (int r4 = 0; r4 < 4; r4++)
            cJ[fr * 4 + r4] = csj[wr * 32 + fr * 16 + (lane >> 4) * 4 + r4];
    float pC[2][8], pR[2][8];
    #pragma unroll
    for (int fc = 0; fc < 2; fc++)
        #pragma unroll
        for (int h = 0; h < 8; h++) { pC[fc][h] = 0.f; pR[fc][h] = 0.f; }
    const int sr = t >> 2, sc = t & 3;
    const bool g0 = (lane >> 4) == 0;
    const bf16x8 zz = {0, 0, 0, 0, 0, 0, 0, 0};
    for (int h = 0; h < 8; h++) {
        __syncthreads();
        *(float4*)&Ah[sr * 40 + sc * 8] = *(const float4*)&qkvnb_cls[(j0 + sr) * 768 + 256 + h * 32 + sc * 8];
        *(float4*)&Bh[sr * 40 + sc * 8] = *(const float4*)&qkvnb_cls[(i0 + sr) * 768 + 0   + h * 32 + sc * 8];
        __syncthreads();
        const int k8 = (lane >> 4) * 8;
        bf16x8 a[2], b[2], arg[2], brg[2];
        #pragma unroll
        for (int fr = 0; fr < 2; fr++) {
            const int row = wr * 32 + fr * 16 + (lane & 15);
            a[fr] = *(const bf16x8*)&Ah[row * 40 + k8];
            arg[fr] = g0 ? *(const bf16x8*)&Kr[row * 72 + h * 8] : zz;
        }
        #pragma unroll
        for (int fc = 0; fc < 2; fc++) {
            const int row = wc * 32 + fc * 16 + (lane & 15);
            b[fc] = *(const bf16x8*)&Bh[row * 40 + k8];
            brg[fc] = g0 ? *(const bf16x8*)&Qr[row * 72 + h * 8] : zz;
        }
        f32x4 acc[2][2], racc[2][2];
        #pragma unroll
        for (int fr = 0; fr < 2; fr++)
            #pragma unroll
            for (int fc = 0; fc < 2; fc++) {
                acc[fr][fc] = (f32x4){0,0,0,0};
                racc[fr][fc] = (f32x4){0,0,0,0};
                acc[fr][fc] = __builtin_amdgcn_mfma_f32_16x16x32_bf16(a[fr], b[fc], acc[fr][fc], 0, 0, 0);
                racc[fr][fc] = __builtin_amdgcn_mfma_f32_16x16x32_bf16(arg[fr], brg[fc], racc[fr][fc], 0, 0, 0);
            }
        #pragma unroll
        for (int fc = 0; fc < 2; fc++) {
            float sC = 0.f, sR = 0.f;
            #pragma unroll
            for (int fr = 0; fr < 2; fr++)
                #pragma unroll
                for (int r4 = 0; r4 < 4; r4++) {
                    const float cj = cJ[fr * 4 + r4];
                    const float lc = (cj > cI[fc]) ? acc[fr][fc][r4] * SCALE * cj : 0.0f;
                    sC += __expf(lc);
                    sR += __expf(racc[fr][fc][r4] * SCALE);
                }
            pC[fc][h] += sC; pR[fc][h] += sR;
        }
    }
    #pragma unroll
    for (int fc = 0; fc < 2; fc++)
        #pragma unroll
        for (int h = 0; h < 8; h++) {
            float v = pC[fc][h]; v += __shfl_xor(v, 16); v += __shfl_xor(v, 32);
            float u = pR[fc][h]; u += __shfl_xor(u, 16); u += __shfl_xor(u, 32);
            if (lane < 16) {
                const int i = i0 + wc * 32 + fc * 16 + lane;
                const int p = blockIdx.x * 2 + wr;
                Dcpart[(p * NT + i) * 8 + h] = v;
                Drpart[(p * NT + i) * 8 + h] = u;
            }
        }
}

// ------ sparse attn @ v: one wave per row i ---------------------------------
// Lane l owns cls dims [4l,4l+4) (head g=l>>3) and reg dim l. All loads
// coalesced; per-head reduces via 8-lane shfl groups; writes objcnt.
__global__ __launch_bounds__(256) void out_v3(
    const float* __restrict__ qkv_cls, const float* __restrict__ qkvn_cls,
    const float* __restrict__ qkv_reg, const float* __restrict__ qkvn_reg,
    const float* __restrict__ cls_score,
    const unsigned* __restrict__ objbits,
    const float* __restrict__ Dcpart, const float* __restrict__ Drpart,
    const float* __restrict__ x_cls, const float* __restrict__ x_reg,
    float* __restrict__ out_cls, float* __restrict__ out_reg,
    int* __restrict__ objcnt)
{
    const int i = (blockIdx.x << 2) + (threadIdx.x >> 6);  // 1536 waves
    const int l = threadIdx.x & 63;
    const int g = l >> 3;

    const float4 q4 = *(const float4*)&qkvn_cls[i * 768 + 4 * l];
    const float  qr = qkvn_reg[i * 192 + l];

    unsigned myw = (l < 48) ? objbits[i * 48 + l] : 0u;
    int cnt = __popc(myw);
    #pragma unroll
    for (int m = 1; m < 64; m <<= 1) cnt += __shfl_xor(cnt, m);

    // denominator gather: sub-lane s sums 6 p's for head g, then 8-lane reduce
    const int s = l & 7;
    float Dcv = 0.f, Drv = 0.f;
    #pragma unroll
    for (int p6 = 0; p6 < 6; p6++) {
        const int p = s * 6 + p6;
        Dcv += Dcpart[(p * NT + i) * 8 + g];
        Drv += Drpart[(p * NT + i) * 8 + g];
    }
    Dcv += __shfl_xor(Dcv, 1); Dcv += __shfl_xor(Dcv, 2); Dcv += __shfl_xor(Dcv, 4);
    Drv += __shfl_xor(Drv, 1); Drv += __shfl_xor(Drv, 2); Drv += __shfl_xor(Drv, 4);

    float a1x = 0.f, a1y = 0.f, a1z = 0.f, a1w = 0.f;
    float a2x = 0.f, a2y = 0.f, a2z = 0.f, a2w = 0.f;
    float rr1 = 0.f, rr2 = 0.f;
    for (int w = 0; w < 48; w++) {
        unsigned bits = __shfl(myw, w);
        while (bits) {
            const int b = __ffs(bits) - 1;
            bits &= bits - 1u;
            const int j = w * 32 + b;
            const float4 k4 = *(const float4*)&qkvn_cls[j * 768 + 256 + 4 * l];
            const float4 v4 = *(const float4*)&qkv_cls [j * 768 + 512 + 4 * l];
            const float  kr = qkvn_reg[j * 192 + 64 + l];
            const float  vr = qkv_reg [j * 192 + 128 + l];
            float dc = q4.x * k4.x + q4.y * k4.y + q4.z * k4.z + q4.w * k4.w;
            dc += __shfl_xor(dc, 1); dc += __shfl_xor(dc, 2); dc += __shfl_xor(dc, 4);
            float dr = qr * kr;
            dr += __shfl_xor(dr, 1); dr += __shfl_xor(dr, 2); dr += __shfl_xor(dr, 4);
            const float cj = cls_score[j];
            const float ec = __expf(dc * SCALE * cj);   // obj => cls_mask==1
            const float er = __expf(dr * SCALE);
            a1x += ec * v4.x; a1y += ec * v4.y; a1z += ec * v4.z; a1w += ec * v4.w;
            a2x += er * v4.x; a2y += er * v4.y; a2z += er * v4.z; a2w += er * v4.w;
            rr1 += ec * vr;   rr2 += er * vr;
        }
    }
    const float iDc = 1.0f / Dcv, iDr = 1.0f / Drv;
    const float hi = 0.5f / (float)cnt;
    float4 o;
    o.x = (a1x * iDc + a2x * iDr) * hi;
    o.y = (a1y * iDc + a2y * iDr) * hi;
    o.z = (a1z * iDc + a2z * iDr) * hi;
    o.w = (a1w * iDc + a2w * iDr) * hi;
    *(float4*)&out_cls[i * 512 + 4 * l] = o;
    out_reg[i * 128 + l] = (rr1 * iDc + rr2 * iDr) * hi;
    // fused concat copies
    *(float4*)&out_cls[i * 512 + 256 + 4 * l] = *(const float4*)&x_cls[i * 256 + 4 * l];
    out_reg[i * 128 + 64 + l] = x_reg[i * 64 + l];
    if (l == 0) objcnt[i] = cnt;
}

// ------ expand bit matrices into 8 head copies ------------------------------
__global__ __launch_bounds__(256) void expand_kernel(
    const unsigned* __restrict__ simbits, const unsigned* __restrict__ objbits,
    const int* __restrict__ objcnt,
    float* __restrict__ sim_out, float* __restrict__ obj_out)
{
    const int idx = blockIdx.x * 256 + threadIdx.x;  // NT*384
    const int i = idx / 384;
    const int j0 = (idx - i * 384) * 4;
    const unsigned sw = simbits[i * 48 + (j0 >> 5)] >> (j0 & 31);
    const unsigned ow = objbits[i * 48 + (j0 >> 5)] >> (j0 & 31);
    const float inv = 1.0f / (float)objcnt[i];
    float4 sv, ov;
    sv.x = (sw & 1u) ? 1.f : 0.f;  ov.x = (ow & 1u) ? inv : 0.f;
    sv.y = (sw & 2u) ? 1.f : 0.f;  ov.y = (ow & 2u) ? inv : 0.f;
    sv.z = (sw & 4u) ? 1.f : 0.f;  ov.z = (ow & 4u) ? inv : 0.f;
    sv.w = (sw & 8u) ? 1.f : 0.f;  ov.w = (ow & 8u) ? inv : 0.f;
    const int base = i * NT + j0;
    #pragma unroll
    for (int h = 0; h < 8; h++) {
        *(float4*)&sim_out[h * (NT * NT) + base] = sv;
        *(float4*)&obj_out[h * (NT * NT) + base] = ov;
    }
}

extern "C" void kernel_launch(void* const* d_in, const int* in_sizes, int n_in,
                              void* d_out, int out_size, void* d_ws, size_t ws_size,
                              hipStream_t stream)
{
    (void)in_sizes; (void)n_in; (void)out_size; (void)ws_size;
    const float* x_cls     = (const float*)d_in[0];
    const float* x_reg     = (const float*)d_in[1];
    const float* cls_score = (const float*)d_in[2];
    const float* fg_score  = (const float*)d_in[3];
    const float* W_cls     = (const float*)d_in[4];
    const float* W_reg     = (const float*)d_in[5];

    float* out = (float*)d_out;
    float* out_cls = out;                  // 786432 floats
    float* out_reg = out + 786432;         // 196608 floats
    float* sim_out = out + 983040;         // 18874368 floats
    float* obj_out = out + 19857408;       // 18874368 floats

    // Large scratch inside output regions (all reads complete before
    // expand_kernel overwrites them; stream-ordered):
    float* qkv_cls  = sim_out;                              // 1,179,648
    float* qkvn_cls = sim_out + 1179648;                    // 1,179,648
    float* qkv_reg  = sim_out + 2359296;                    //   294,912
    float* qkvn_reg = sim_out + 2654208;                    //   294,912
    unsigned short* qkvnb_cls = (unsigned short*)(sim_out + 2949120);  // 1,179,648 u16
    unsigned short* qkvnb_reg = (unsigned short*)(sim_out + 3538944);  //   294,912 u16
    float* Dcpart   = obj_out;                              //   589,824 (48*1536*8)
    float* Drpart   = obj_out + 589824;                     //   589,824

    // Small scratch in d_ws (~0.6 MB)
    char* ws = (char*)d_ws;
    unsigned* simbits = (unsigned*)ws;             // 73728 words
    unsigned* objbits = simbits + 73728;           // 73728 words
    int*      objcnt  = (int*)(objbits + 73728);   // 1536

    gemm_norm<<<dim3(12, 24), 256, 0, stream>>>(x_cls, W_cls, qkv_cls, qkvn_cls, qkvnb_cls, 256, 768, 8);
    gemm_norm<<<dim3(3, 24), 256, 0, stream>>>(x_reg, W_reg, qkv_reg, qkvn_reg, qkvnb_reg, 64, 192, 2);
    bits_mfma<<<dim3(24, 24), 256, 0, stream>>>(qkvnb_cls, qkvnb_reg, cls_score, fg_score,
                                                simbits, objbits);
    denom_mfma<<<dim3(24, 24), 256, 0, stream>>>(qkvnb_cls, qkvnb_reg, cls_score, Dcpart, Drpart);
    out_v3<<<384, 256, 0, stream>>>(qkv_cls, qkvn_cls, qkv_reg, qkvn_reg, cls_score,
                                    objbits, Dcpart, Drpart, x_cls, x_reg,
                                    out_cls, out_reg, objcnt);
    expand_kernel<<<2304, 256, 0, stream>>>(simbits, objbits, objcnt, sim_out, obj_out);
}

// Round 7
// 93.428 us; speedup vs baseline: 2.9203x; 1.0368x over previous
//
#include <hip/hip_runtime.h>
#include <hip/hip_bf16.h>

#define NT 1536
#define SCALE 0.17677669529663687f  // (256/8)^-0.5

typedef __attribute__((ext_vector_type(8))) short bf16x8;
typedef __attribute__((ext_vector_type(4))) float f32x4;

static __device__ __forceinline__ unsigned short f2b(float x) {
    __hip_bfloat16 h = __float2bfloat16(x);
    union { __hip_bfloat16 b; unsigned short u; } cv; cv.b = h; return cv.u;
}

// ------ GEMM + fused per-head L2 normalize + bf16 emit (cls & reg fused) ----
__global__ __launch_bounds__(256) void gemm_norm2(
    const float* __restrict__ xc, const float* __restrict__ xr,
    const float* __restrict__ Wc, const float* __restrict__ Wr,
    float* __restrict__ qkv_c, float* __restrict__ qkvn_c, unsigned short* __restrict__ qb_c,
    float* __restrict__ qkv_r, float* __restrict__ qkvn_r, unsigned short* __restrict__ qb_r)
{
    const float *A, *B;
    float *qkv, *qkvn;
    unsigned short* qkvnb;
    int K, NN, glanes;
    if (blockIdx.z == 0) {
        A = xc; B = Wc; qkv = qkv_c; qkvn = qkvn_c; qkvnb = qb_c;
        K = 256; NN = 768; glanes = 8;
    } else {
        if (blockIdx.x >= 3) return;
        A = xr; B = Wr; qkv = qkv_r; qkvn = qkvn_r; qkvnb = qb_r;
        K = 64; NN = 192; glanes = 2;
    }
    __shared__ float As[16][68];
    __shared__ float Bs[16][68];
    const int t = threadIdx.x;
    const int tx = t & 15, ty = t >> 4;
    const int i0 = blockIdx.y * 64, j0 = blockIdx.x * 64;
    float acc[4][4] = {};
    for (int k0 = 0; k0 < K; k0 += 16) {
        float4 av = *(const float4*)&A[(i0 + (t >> 2)) * K + k0 + (t & 3) * 4];
        float4 bv = *(const float4*)&B[(k0 + (t >> 4)) * NN + j0 + tx * 4];
        __syncthreads();
        As[(t & 3) * 4 + 0][t >> 2] = av.x;
        As[(t & 3) * 4 + 1][t >> 2] = av.y;
        As[(t & 3) * 4 + 2][t >> 2] = av.z;
        As[(t & 3) * 4 + 3][t >> 2] = av.w;
        *(float4*)&Bs[t >> 4][tx * 4] = bv;
        __syncthreads();
        #pragma unroll
        for (int kk = 0; kk < 16; kk++) {
            float4 a = *(const float4*)&As[kk][ty * 4];
            float4 b = *(const float4*)&Bs[kk][tx * 4];
            float ar_[4] = {a.x, a.y, a.z, a.w};
            float br_[4] = {b.x, b.y, b.z, b.w};
            #pragma unroll
            for (int r = 0; r < 4; r++)
                #pragma unroll
                for (int c = 0; c < 4; c++)
                    acc[r][c] += ar_[r] * br_[c];
        }
    }
    #pragma unroll
    for (int r = 0; r < 4; r++) {
        const int row = i0 + ty * 4 + r, col = j0 + tx * 4;
        float4 o = {acc[r][0], acc[r][1], acc[r][2], acc[r][3]};
        *(float4*)&qkv[row * NN + col] = o;
        float s = o.x * o.x + o.y * o.y + o.z * o.z + o.w * o.w;
        for (int m = 1; m < glanes; m <<= 1) s += __shfl_xor(s, m);
        const float inv = 1.0f / sqrtf(s);
        float4 n = {o.x * inv, o.y * inv, o.z * inv, o.w * inv};
        *(float4*)&qkvn[row * NN + col] = n;
        ushort4 nb;
        nb.x = f2b(n.x); nb.y = f2b(n.y); nb.z = f2b(n.z); nb.w = f2b(n.w);
        *(ushort4*)&qkvnb[row * NN + col] = nb;
    }
}

// ------ fused: sim/obj bit matrices + softmax denominator partials ----------
__global__ __launch_bounds__(256) void tile_kernel(
    const unsigned short* __restrict__ qkvnb_cls, const unsigned short* __restrict__ qkvnb_reg,
    const float* __restrict__ cls_score, const float* __restrict__ fg_score,
    unsigned* __restrict__ simbits, unsigned* __restrict__ objbits,
    float* __restrict__ Dcpart, float* __restrict__ Drpart)
{
    __shared__ short Ai[64 * 40], Bj[64 * 40];     // reused across both phases
    __shared__ short Kr[64 * 72], Qr[64 * 72];     // reg full-K
    __shared__ float csi[64], csj[64], fgi[64], fgj[64];
    __shared__ unsigned simw[64][2], objw[64][2];
    const int t = threadIdx.x;
    const int lane = t & 63;
    const int wv = t >> 6, wr = wv >> 1, wc = wv & 1;
    const int i0 = blockIdx.y * 64, j0 = blockIdx.x * 64;
    if (t < 64)       { csi[t] = cls_score[i0 + t]; fgi[t] = fg_score[i0 + t]; }
    else if (t < 128) { csj[t - 64] = cls_score[j0 + t - 64]; fgj[t - 64] = fg_score[j0 + t - 64]; }
    // stage reg K/Q full rows (for denominator phase)
    #pragma unroll
    for (int it = 0; it < 2; it++) {
        const int u = it * 256 + t;
        const int r = u >> 3, c = u & 7;
        *(float4*)&Kr[r * 72 + c * 8] = *(const float4*)&qkvnb_reg[(j0 + r) * 192 + 64 + c * 8];
        *(float4*)&Qr[r * 72 + c * 8] = *(const float4*)&qkvnb_reg[(i0 + r) * 192 + 0 + c * 8];
    }
    const int sr = t >> 2, sc = t & 3;

    // ---------------- phase A: bit masks (V·V cls, Vr·Vr reg) ----------------
    f32x4 ac[2][2], ar[2][2];
    #pragma unroll
    for (int a = 0; a < 2; a++)
        #pragma unroll
        for (int b = 0; b < 2; b++) { ac[a][b] = (f32x4){0,0,0,0}; ar[a][b] = (f32x4){0,0,0,0}; }
    for (int ks = 0; ks < 8; ks++) {
        __syncthreads();
        *(float4*)&Ai[sr * 40 + sc * 8] = *(const float4*)&qkvnb_cls[(i0 + sr) * 768 + 512 + ks * 32 + sc * 8];
        *(float4*)&Bj[sr * 40 + sc * 8] = *(const float4*)&qkvnb_cls[(j0 + sr) * 768 + 512 + ks * 32 + sc * 8];
        __syncthreads();
        const int k8 = (lane >> 4) * 8;
        bf16x8 af[2], bf_[2];
        #pragma unroll
        for (int fr = 0; fr < 2; fr++)
            af[fr] = *(const bf16x8*)&Ai[(wr * 32 + fr * 16 + (lane & 15)) * 40 + k8];
        #pragma unroll
        for (int fc = 0; fc < 2; fc++)
            bf_[fc] = *(const bf16x8*)&Bj[(wc * 32 + fc * 16 + (lane & 15)) * 40 + k8];
        #pragma unroll
        for (int fr = 0; fr < 2; fr++)
            #pragma unroll
            for (int fc = 0; fc < 2; fc++)
                ac[fr][fc] = __builtin_amdgcn_mfma_f32_16x16x32_bf16(af[fr], bf_[fc], ac[fr][fc], 0, 0, 0);
    }
    for (int ks = 0; ks < 2; ks++) {
        __syncthreads();
        *(float4*)&Ai[sr * 40 + sc * 8] = *(const float4*)&qkvnb_reg[(i0 + sr) * 192 + 128 + ks * 32 + sc * 8];
        *(float4*)&Bj[sr * 40 + sc * 8] = *(const float4*)&qkvnb_reg[(j0 + sr) * 192 + 128 + ks * 32 + sc * 8];
        __syncthreads();
        const int k8 = (lane >> 4) * 8;
        bf16x8 af[2], bf_[2];
        #pragma unroll
        for (int fr = 0; fr < 2; fr++)
            af[fr] = *(const bf16x8*)&Ai[(wr * 32 + fr * 16 + (lane & 15)) * 40 + k8];
        #pragma unroll
        for (int fc = 0; fc < 2; fc++)
            bf_[fc] = *(const bf16x8*)&Bj[(wc * 32 + fc * 16 + (lane & 15)) * 40 + k8];
        #pragma unroll
        for (int fr = 0; fr < 2; fr++)
            #pragma unroll
            for (int fc = 0; fc < 2; fc++)
                ar[fr][fc] = __builtin_amdgcn_mfma_f32_16x16x32_bf16(af[fr], bf_[fc], ar[fr][fc], 0, 0, 0);
    }
    #pragma unroll
    for (int fr = 0; fr < 2; fr++)
        #pragma unroll
        for (int r4 = 0; r4 < 4; r4++) {
            const int rloc = wr * 32 + fr * 16 + (lane >> 4) * 4 + r4;
            const float ci = csi[rloc] - 0.1f, fgv = fgi[rloc] - 0.1f;
            unsigned sm[2], om[2];
            #pragma unroll
            for (int fc = 0; fc < 2; fc++) {
                const int cloc = wc * 32 + fc * 16 + (lane & 15);
                const bool clsb = csj[cloc] > ci;
                const bool fgb  = fgj[cloc] > fgv;
                const bool sim = (ac[fr][fc][r4] * 0.125f > 0.75f) && clsb && fgb;
                const bool obj = sim && (ar[fr][fc][r4] * 0.125f > 0.75f);
                unsigned long long bs = __ballot(sim);
                unsigned long long bo = __ballot(obj);
                const int g = lane >> 4;
                sm[fc] = (unsigned)((bs >> (16 * g)) & 0xFFFFull);
                om[fc] = (unsigned)((bo >> (16 * g)) & 0xFFFFull);
            }
            if ((lane & 15) == 0) {
                simw[rloc][wc] = sm[0] | (sm[1] << 16);
                objw[rloc][wc] = om[0] | (om[1] << 16);
            }
        }
    __syncthreads();
    if (t < 128) {
        const int row = t >> 1, w = t & 1;
        simbits[(i0 + row) * 48 + blockIdx.x * 2 + w] = simw[row][w];
        objbits[(i0 + row) * 48 + blockIdx.x * 2 + w] = objw[row][w];
    }

    // ---------------- phase B: denominators (K·Q per head; C rows = j) -------
    float cI[2], cJ[8];
    #pragma unroll
    for (int fc = 0; fc < 2; fc++) cI[fc] = csi[wc * 32 + fc * 16 + (lane & 15)] - 0.1f;
    #pragma unroll
    for (int fr = 0; fr < 2; fr++)
        #pragma unroll
        for (int r4 = 0; r4 < 4; r4++)
            cJ[fr * 4 + r4] = csj[wr * 32 + fr * 16 + (lane >> 4) * 4 + r4];
    float pC[2][8], pR[2][8];
    #pragma unroll
    for (int fc = 0; fc < 2; fc++)
        #pragma unroll
        for (int h = 0; h < 8; h++) { pC[fc][h] = 0.f; pR[fc][h] = 0.f; }
    const bool g0 = (lane >> 4) == 0;
    const bf16x8 zz = {0, 0, 0, 0, 0, 0, 0, 0};
    for (int h = 0; h < 8; h++) {
        __syncthreads();
        *(float4*)&Ai[sr * 40 + sc * 8] = *(const float4*)&qkvnb_cls[(j0 + sr) * 768 + 256 + h * 32 + sc * 8];
        *(float4*)&Bj[sr * 40 + sc * 8] = *(const float4*)&qkvnb_cls[(i0 + sr) * 768 + 0   + h * 32 + sc * 8];
        __syncthreads();
        const int k8 = (lane >> 4) * 8;
        bf16x8 a[2], b[2], arg[2], brg[2];
        #pragma unroll
        for (int fr = 0; fr < 2; fr++) {
            const int row = wr * 32 + fr * 16 + (lane & 15);
            a[fr] = *(const bf16x8*)&Ai[row * 40 + k8];
            arg[fr] = g0 ? *(const bf16x8*)&Kr[row * 72 + h * 8] : zz;
        }
        #pragma unroll
        for (int fc = 0; fc < 2; fc++) {
            const int row = wc * 32 + fc * 16 + (lane & 15);
            b[fc] = *(const bf16x8*)&Bj[row * 40 + k8];
            brg[fc] = g0 ? *(const bf16x8*)&Qr[row * 72 + h * 8] : zz;
        }
        f32x4 acc[2][2], racc[2][2];
        #pragma unroll
        for (int fr = 0; fr < 2; fr++)
            #pragma unroll
            for (int fc = 0; fc < 2; fc++) {
                acc[fr][fc] = (f32x4){0,0,0,0};
                racc[fr][fc] = (f32x4){0,0,0,0};
                acc[fr][fc] = __builtin_amdgcn_mfma_f32_16x16x32_bf16(a[fr], b[fc], acc[fr][fc], 0, 0, 0);
                racc[fr][fc] = __builtin_amdgcn_mfma_f32_16x16x32_bf16(arg[fr], brg[fc], racc[fr][fc], 0, 0, 0);
            }
        #pragma unroll
        for (int fc = 0; fc < 2; fc++) {
            float sC = 0.f, sR = 0.f;
            #pragma unroll
            for (int fr = 0; fr < 2; fr++)
                #pragma unroll
                for (int r4 = 0; r4 < 4; r4++) {
                    const float cj = cJ[fr * 4 + r4];
                    const float lc = (cj > cI[fc]) ? acc[fr][fc][r4] * SCALE * cj : 0.0f;
                    sC += __expf(lc);
                    sR += __expf(racc[fr][fc][r4] * SCALE);
                }
            pC[fc][h] += sC; pR[fc][h] += sR;
        }
    }
    #pragma unroll
    for (int fc = 0; fc < 2; fc++)
        #pragma unroll
        for (int h = 0; h < 8; h++) {
            float v = pC[fc][h]; v += __shfl_xor(v, 16); v += __shfl_xor(v, 32);
            float u = pR[fc][h]; u += __shfl_xor(u, 16); u += __shfl_xor(u, 32);
            if (lane < 16) {
                const int i = i0 + wc * 32 + fc * 16 + lane;
                const int p = blockIdx.x * 2 + wr;
                Dcpart[(p * NT + i) * 8 + h] = v;
                Drpart[(p * NT + i) * 8 + h] = u;
            }
        }
}

// ------ per-row finish: sparse attn-out + concat + mask expansion -----------
__global__ __launch_bounds__(256) void finish_row(
    const float* __restrict__ qkv_cls, const float* __restrict__ qkvn_cls,
    const float* __restrict__ qkv_reg, const float* __restrict__ qkvn_reg,
    const float* __restrict__ cls_score,
    const unsigned* __restrict__ simbits, const unsigned* __restrict__ objbits,
    const float* __restrict__ Dcpart, const float* __restrict__ Drpart,
    const float* __restrict__ x_cls, const float* __restrict__ x_reg,
    float* __restrict__ out_cls, float* __restrict__ out_reg,
    float* __restrict__ sim_out, float* __restrict__ obj_out)
{
    const int i = blockIdx.x;
    const int t = threadIdx.x;
    __shared__ unsigned sw[48], ow[48];
    __shared__ float inv_sh;
    __shared__ int cnt_sh;
    if (t < 48)      sw[t] = simbits[i * 48 + t];
    else if (t < 96) ow[t - 48] = objbits[i * 48 + t - 48];
    __syncthreads();
    if (t < 64) {
        int c = (t < 48) ? __popc(ow[t]) : 0;
        #pragma unroll
        for (int m = 1; m < 64; m <<= 1) c += __shfl_xor(c, m);
        if (t == 0) { cnt_sh = c; inv_sh = 1.0f / (float)c; }
    }
    __syncthreads();
    const int cnt = cnt_sh;
    const float inv = inv_sh;

    if (t < 64) {
        // sparse attn output (wave 0); lane l owns cls dims [4l,4l+4), reg dim l
        const int l = t;
        const int g = l >> 3;
        const float4 q4 = *(const float4*)&qkvn_cls[i * 768 + 4 * l];
        const float  qr = qkvn_reg[i * 192 + l];
        const int s = l & 7;
        float Dcv = 0.f, Drv = 0.f;
        #pragma unroll
        for (int p6 = 0; p6 < 6; p6++) {
            const int p = s * 6 + p6;
            Dcv += Dcpart[(p * NT + i) * 8 + g];
            Drv += Drpart[(p * NT + i) * 8 + g];
        }
        Dcv += __shfl_xor(Dcv, 1); Dcv += __shfl_xor(Dcv, 2); Dcv += __shfl_xor(Dcv, 4);
        Drv += __shfl_xor(Drv, 1); Drv += __shfl_xor(Drv, 2); Drv += __shfl_xor(Drv, 4);
        float a1x = 0.f, a1y = 0.f, a1z = 0.f, a1w = 0.f;
        float a2x = 0.f, a2y = 0.f, a2z = 0.f, a2w = 0.f;
        float rr1 = 0.f, rr2 = 0.f;
        for (int w = 0; w < 48; w++) {
            unsigned bits = ow[w];
            while (bits) {
                const int b = __ffs(bits) - 1;
                bits &= bits - 1u;
                const int j = w * 32 + b;
                const float4 k4 = *(const float4*)&qkvn_cls[j * 768 + 256 + 4 * l];
                const float4 v4 = *(const float4*)&qkv_cls [j * 768 + 512 + 4 * l];
                const float  kr = qkvn_reg[j * 192 + 64 + l];
                const float  vr = qkv_reg [j * 192 + 128 + l];
                float dc = q4.x * k4.x + q4.y * k4.y + q4.z * k4.z + q4.w * k4.w;
                dc += __shfl_xor(dc, 1); dc += __shfl_xor(dc, 2); dc += __shfl_xor(dc, 4);
                float dr = qr * kr;
                dr += __shfl_xor(dr, 1); dr += __shfl_xor(dr, 2); dr += __shfl_xor(dr, 4);
                const float cj = cls_score[j];
                const float ec = __expf(dc * SCALE * cj);   // obj => cls_mask==1
                const float er = __expf(dr * SCALE);
                a1x += ec * v4.x; a1y += ec * v4.y; a1z += ec * v4.z; a1w += ec * v4.w;
                a2x += er * v4.x; a2y += er * v4.y; a2z += er * v4.z; a2w += er * v4.w;
                rr1 += ec * vr;   rr2 += er * vr;
            }
        }
        const float iDc = 1.0f / Dcv, iDr = 1.0f / Drv;
        const float hi = 0.5f / (float)cnt;
        float4 o;
        o.x = (a1x * iDc + a2x * iDr) * hi;
        o.y = (a1y * iDc + a2y * iDr) * hi;
        o.z = (a1z * iDc + a2z * iDr) * hi;
        o.w = (a1w * iDc + a2w * iDr) * hi;
        *(float4*)&out_cls[i * 512 + 4 * l] = o;
        out_reg[i * 128 + l] = (rr1 * iDc + rr2 * iDr) * hi;
        *(float4*)&out_cls[i * 512 + 256 + 4 * l] = *(const float4*)&x_cls[i * 256 + 4 * l];
        out_reg[i * 128 + 64 + l] = x_reg[i * 64 + l];
    }

    // mask expansion for this row: 2 arrays x 8 heads x 1536 cols
    #pragma unroll
    for (int arr = 0; arr < 2; arr++) {
        const unsigned* wsrc = arr ? ow : sw;
        float* base0 = arr ? obj_out : sim_out;
        const float on = arr ? inv : 1.0f;
        #pragma unroll
        for (int h = 0; h < 8; h++) {
            float* base = base0 + h * (NT * NT) + i * NT;
            {
                const int c4 = t;
                const unsigned wo = wsrc[c4 >> 3] >> ((c4 & 7) * 4);
                float4 v;
                v.x = (wo & 1u) ? on : 0.f;
                v.y = (wo & 2u) ? on : 0.f;
                v.z = (wo & 4u) ? on : 0.f;
                v.w = (wo & 8u) ? on : 0.f;
                *(float4*)&base[c4 * 4] = v;
            }
            if (t < 128) {
                const int c4 = 256 + t;
                const unsigned wo = wsrc[c4 >> 3] >> ((c4 & 7) * 4);
                float4 v;
                v.x = (wo & 1u) ? on : 0.f;
                v.y = (wo & 2u) ? on : 0.f;
                v.z = (wo & 4u) ? on : 0.f;
                v.w = (wo & 8u) ? on : 0.f;
                *(float4*)&base[c4 * 4] = v;
            }
        }
    }
}

extern "C" void kernel_launch(void* const* d_in, const int* in_sizes, int n_in,
                              void* d_out, int out_size, void* d_ws, size_t ws_size,
                              hipStream_t stream)
{
    (void)in_sizes; (void)n_in; (void)out_size; (void)ws_size;
    const float* x_cls     = (const float*)d_in[0];
    const float* x_reg     = (const float*)d_in[1];
    const float* cls_score = (const float*)d_in[2];
    const float* fg_score  = (const float*)d_in[3];
    const float* W_cls     = (const float*)d_in[4];
    const float* W_reg     = (const float*)d_in[5];

    float* out = (float*)d_out;
    float* out_cls = out;                  // 786432 floats
    float* out_reg = out + 786432;         // 196608 floats
    float* sim_out = out + 983040;         // 18874368 floats
    float* obj_out = out + 19857408;       // 18874368 floats

    // All scratch in d_ws (~25 MB; d_ws is large per harness poison fills)
    float* wsf = (float*)d_ws;
    float* qkv_cls  = wsf;                              // 1,179,648
    float* qkvn_cls = wsf + 1179648;                    // 1,179,648
    float* qkv_reg  = wsf + 2359296;                    //   294,912
    float* qkvn_reg = wsf + 2654208;                    //   294,912
    unsigned short* qkvnb_cls = (unsigned short*)(wsf + 2949120);  // 1,179,648 u16
    unsigned short* qkvnb_reg = (unsigned short*)(wsf + 3538944);  //   294,912 u16
    float* Dcpart   = wsf + 3686400;                    //   589,824 (48*1536*8)
    float* Drpart   = wsf + 4276224;                    //   589,824
    unsigned* simbits = (unsigned*)(wsf + 4866048);     //    73,728 u32
    unsigned* objbits = simbits + 73728;                //    73,728 u32

    gemm_norm2<<<dim3(12, 24, 2), 256, 0, stream>>>(
        x_cls, x_reg, W_cls, W_reg,
        qkv_cls, qkvn_cls, qkvnb_cls, qkv_reg, qkvn_reg, qkvnb_reg);
    tile_kernel<<<dim3(24, 24), 256, 0, stream>>>(
        qkvnb_cls, qkvnb_reg, cls_score, fg_score,
        simbits, objbits, Dcpart, Drpart);
    finish_row<<<NT, 256, 0, stream>>>(
        qkv_cls, qkvn_cls, qkv_reg, qkvn_reg, cls_score,
        simbits, objbits, Dcpart, Drpart, x_cls, x_reg,
        out_cls, out_reg, sim_out, obj_out);
}

// Round 8
// 85.691 us; speedup vs baseline: 3.1840x; 1.0903x over previous
//
#include <hip/hip_runtime.h>
#include <hip/hip_bf16.h>

#define NT 1536
#define SCALE 0.17677669529663687f  // (256/8)^-0.5

typedef __attribute__((ext_vector_type(8))) short bf16x8;
typedef __attribute__((ext_vector_type(4))) float f32x4;

static __device__ __forceinline__ unsigned short f2b(float x) {
    __hip_bfloat16 h = __float2bfloat16(x);
    union { __hip_bfloat16 b; unsigned short u; } cv; cv.b = h; return cv.u;
}

// ------ GEMM + fused per-head L2 normalize + bf16 emit (cls & reg fused) ----
__global__ __launch_bounds__(256) void gemm_norm2(
    const float* __restrict__ xc, const float* __restrict__ xr,
    const float* __restrict__ Wc, const float* __restrict__ Wr,
    float* __restrict__ qkv_c, float* __restrict__ qkvn_c, unsigned short* __restrict__ qb_c,
    float* __restrict__ qkv_r, float* __restrict__ qkvn_r, unsigned short* __restrict__ qb_r)
{
    const float *A, *B;
    float *qkv, *qkvn;
    unsigned short* qkvnb;
    int K, NN, glanes;
    if (blockIdx.z == 0) {
        A = xc; B = Wc; qkv = qkv_c; qkvn = qkvn_c; qkvnb = qb_c;
        K = 256; NN = 768; glanes = 8;
    } else {
        if (blockIdx.x >= 3) return;
        A = xr; B = Wr; qkv = qkv_r; qkvn = qkvn_r; qkvnb = qb_r;
        K = 64; NN = 192; glanes = 2;
    }
    __shared__ float As[16][68];
    __shared__ float Bs[16][68];
    const int t = threadIdx.x;
    const int tx = t & 15, ty = t >> 4;
    const int i0 = blockIdx.y * 64, j0 = blockIdx.x * 64;
    float acc[4][4] = {};
    for (int k0 = 0; k0 < K; k0 += 16) {
        float4 av = *(const float4*)&A[(i0 + (t >> 2)) * K + k0 + (t & 3) * 4];
        float4 bv = *(const float4*)&B[(k0 + (t >> 4)) * NN + j0 + tx * 4];
        __syncthreads();
        As[(t & 3) * 4 + 0][t >> 2] = av.x;
        As[(t & 3) * 4 + 1][t >> 2] = av.y;
        As[(t & 3) * 4 + 2][t >> 2] = av.z;
        As[(t & 3) * 4 + 3][t >> 2] = av.w;
        *(float4*)&Bs[t >> 4][tx * 4] = bv;
        __syncthreads();
        #pragma unroll
        for (int kk = 0; kk < 16; kk++) {
            float4 a = *(const float4*)&As[kk][ty * 4];
            float4 b = *(const float4*)&Bs[kk][tx * 4];
            float ar_[4] = {a.x, a.y, a.z, a.w};
            float br_[4] = {b.x, b.y, b.z, b.w};
            #pragma unroll
            for (int r = 0; r < 4; r++)
                #pragma unroll
                for (int c = 0; c < 4; c++)
                    acc[r][c] += ar_[r] * br_[c];
        }
    }
    #pragma unroll
    for (int r = 0; r < 4; r++) {
        const int row = i0 + ty * 4 + r, col = j0 + tx * 4;
        float4 o = {acc[r][0], acc[r][1], acc[r][2], acc[r][3]};
        *(float4*)&qkv[row * NN + col] = o;
        float s = o.x * o.x + o.y * o.y + o.z * o.z + o.w * o.w;
        for (int m = 1; m < glanes; m <<= 1) s += __shfl_xor(s, m);
        const float inv = 1.0f / sqrtf(s);
        float4 n = {o.x * inv, o.y * inv, o.z * inv, o.w * inv};
        *(float4*)&qkvn[row * NN + col] = n;
        ushort4 nb;
        nb.x = f2b(n.x); nb.y = f2b(n.y); nb.z = f2b(n.z); nb.w = f2b(n.w);
        *(ushort4*)&qkvnb[row * NN + col] = nb;
    }
}

// ------ fused bits + denominators, register-prefetched staging --------------
__global__ __launch_bounds__(256) void tile2(
    const unsigned short* __restrict__ qb_cls, const unsigned short* __restrict__ qb_reg,
    const float* __restrict__ qkvn_reg,
    const float* __restrict__ cls_score, const float* __restrict__ fg_score,
    unsigned* __restrict__ simbits, unsigned* __restrict__ objbits,
    float* __restrict__ Dcpart, float* __restrict__ Drpart)
{
    __shared__ short Ai[64 * 40], Bj[64 * 40];
    __shared__ float Krf[64][68], Qrf[64][68];   // f32 reg K rows (j) / Q rows (i)
    __shared__ float csi[64], csj[64], fgi[64], fgj[64];
    __shared__ unsigned simw[64][2], objw[64][2];
    const int t = threadIdx.x;
    const int lane = t & 63;
    const int wv = t >> 6, wr = wv >> 1, wc = wv & 1;
    const int i0 = blockIdx.y * 64, j0 = blockIdx.x * 64;
    if (t < 64)       { csi[t] = cls_score[i0 + t]; fgi[t] = fg_score[i0 + t]; }
    else if (t < 128) { csj[t - 64] = cls_score[j0 + t - 64]; fgj[t - 64] = fg_score[j0 + t - 64]; }
    // stage f32 reg rows (for denominator phase): 4 rounds x 256 thr x float4
    #pragma unroll
    for (int it = 0; it < 4; it++) {
        const int u = it * 256 + t;
        const int r = u >> 4, c4 = (u & 15) * 4;
        *(float4*)&Qrf[r][c4] = *(const float4*)&qkvn_reg[(i0 + r) * 192 + 0 + c4];
        *(float4*)&Krf[r][c4] = *(const float4*)&qkvn_reg[(j0 + r) * 192 + 64 + c4];
    }
    const int sr = t >> 2, sc = t & 3;

    // ---------------- phase A: bit masks ----------------
    f32x4 ac[2][2], ar[2][2];
    #pragma unroll
    for (int a = 0; a < 2; a++)
        #pragma unroll
        for (int b = 0; b < 2; b++) { ac[a][b] = (f32x4){0,0,0,0}; ar[a][b] = (f32x4){0,0,0,0}; }
    float4 ra = *(const float4*)&qb_cls[(i0 + sr) * 768 + 512 + sc * 8];
    float4 rb = *(const float4*)&qb_cls[(j0 + sr) * 768 + 512 + sc * 8];
    for (int ks = 0; ks < 10; ks++) {
        __syncthreads();
        *(float4*)&Ai[sr * 40 + sc * 8] = ra;
        *(float4*)&Bj[sr * 40 + sc * 8] = rb;
        if (ks < 7) {
            ra = *(const float4*)&qb_cls[(i0 + sr) * 768 + 512 + (ks + 1) * 32 + sc * 8];
            rb = *(const float4*)&qb_cls[(j0 + sr) * 768 + 512 + (ks + 1) * 32 + sc * 8];
        } else if (ks < 9) {
            const int k2 = ks - 7;
            ra = *(const float4*)&qb_reg[(i0 + sr) * 192 + 128 + k2 * 32 + sc * 8];
            rb = *(const float4*)&qb_reg[(j0 + sr) * 192 + 128 + k2 * 32 + sc * 8];
        }
        __syncthreads();
        const int k8 = (lane >> 4) * 8;
        bf16x8 af[2], bf_[2];
        #pragma unroll
        for (int fr = 0; fr < 2; fr++)
            af[fr] = *(const bf16x8*)&Ai[(wr * 32 + fr * 16 + (lane & 15)) * 40 + k8];
        #pragma unroll
        for (int fc = 0; fc < 2; fc++)
            bf_[fc] = *(const bf16x8*)&Bj[(wc * 32 + fc * 16 + (lane & 15)) * 40 + k8];
        if (ks < 8) {
            #pragma unroll
            for (int fr = 0; fr < 2; fr++)
                #pragma unroll
                for (int fc = 0; fc < 2; fc++)
                    ac[fr][fc] = __builtin_amdgcn_mfma_f32_16x16x32_bf16(af[fr], bf_[fc], ac[fr][fc], 0, 0, 0);
        } else {
            #pragma unroll
            for (int fr = 0; fr < 2; fr++)
                #pragma unroll
                for (int fc = 0; fc < 2; fc++)
                    ar[fr][fc] = __builtin_amdgcn_mfma_f32_16x16x32_bf16(af[fr], bf_[fc], ar[fr][fc], 0, 0, 0);
        }
    }
    #pragma unroll
    for (int fr = 0; fr < 2; fr++)
        #pragma unroll
        for (int r4 = 0; r4 < 4; r4++) {
            const int rloc = wr * 32 + fr * 16 + (lane >> 4) * 4 + r4;
            const float ci = csi[rloc] - 0.1f, fgv = fgi[rloc] - 0.1f;
            unsigned sm[2], om[2];
            #pragma unroll
            for (int fc = 0; fc < 2; fc++) {
                const int cloc = wc * 32 + fc * 16 + (lane & 15);
                const bool clsb = csj[cloc] > ci;
                const bool fgb  = fgj[cloc] > fgv;
                const bool sim = (ac[fr][fc][r4] * 0.125f > 0.75f) && clsb && fgb;
                const bool obj = sim && (ar[fr][fc][r4] * 0.125f > 0.75f);
                unsigned long long bs = __ballot(sim);
                unsigned long long bo = __ballot(obj);
                const int g = lane >> 4;
                sm[fc] = (unsigned)((bs >> (16 * g)) & 0xFFFFull);
                om[fc] = (unsigned)((bo >> (16 * g)) & 0xFFFFull);
            }
            if ((lane & 15) == 0) {
                simw[rloc][wc] = sm[0] | (sm[1] << 16);
                objw[rloc][wc] = om[0] | (om[1] << 16);
            }
        }
    __syncthreads();
    if (t < 128) {
        const int row = t >> 1, w = t & 1;
        simbits[(i0 + row) * 48 + blockIdx.x * 2 + w] = simw[row][w];
        objbits[(i0 + row) * 48 + blockIdx.x * 2 + w] = objw[row][w];
    }

    // ---------------- phase B: denominators (cls MFMA; reg VALU) -------------
    float cI[2], cJ[8];
    #pragma unroll
    for (int fc = 0; fc < 2; fc++) cI[fc] = csi[wc * 32 + fc * 16 + (lane & 15)] - 0.1f;
    #pragma unroll
    for (int fr = 0; fr < 2; fr++)
        #pragma unroll
        for (int r4 = 0; r4 < 4; r4++)
            cJ[fr * 4 + r4] = csj[wr * 32 + fr * 16 + (lane >> 4) * 4 + r4];
    float pC[2][8], pR[2][8];
    ra = *(const float4*)&qb_cls[(j0 + sr) * 768 + 256 + sc * 8];
    rb = *(const float4*)&qb_cls[(i0 + sr) * 768 + 0   + sc * 8];
    for (int h = 0; h < 8; h++) {
        __syncthreads();
        *(float4*)&Ai[sr * 40 + sc * 8] = ra;
        *(float4*)&Bj[sr * 40 + sc * 8] = rb;
        if (h < 7) {
            ra = *(const float4*)&qb_cls[(j0 + sr) * 768 + 256 + (h + 1) * 32 + sc * 8];
            rb = *(const float4*)&qb_cls[(i0 + sr) * 768 + 0   + (h + 1) * 32 + sc * 8];
        }
        __syncthreads();
        const int k8 = (lane >> 4) * 8;
        bf16x8 a[2], b[2];
        #pragma unroll
        for (int fr = 0; fr < 2; fr++)
            a[fr] = *(const bf16x8*)&Ai[(wr * 32 + fr * 16 + (lane & 15)) * 40 + k8];
        #pragma unroll
        for (int fc = 0; fc < 2; fc++)
            b[fc] = *(const bf16x8*)&Bj[(wc * 32 + fc * 16 + (lane & 15)) * 40 + k8];
        f32x4 acc[2][2];
        #pragma unroll
        for (int fr = 0; fr < 2; fr++)
            #pragma unroll
            for (int fc = 0; fc < 2; fc++) {
                acc[fr][fc] = (f32x4){0,0,0,0};
                acc[fr][fc] = __builtin_amdgcn_mfma_f32_16x16x32_bf16(a[fr], b[fc], acc[fr][fc], 0, 0, 0);
            }
        #pragma unroll
        for (int fc = 0; fc < 2; fc++) {
            const int iloc = wc * 32 + fc * 16 + (lane & 15);
            float qv[8];
            #pragma unroll
            for (int d = 0; d < 8; d++) qv[d] = Qrf[iloc][h * 8 + d];
            float sC = 0.f, sR = 0.f;
            #pragma unroll
            for (int fr = 0; fr < 2; fr++)
                #pragma unroll
                for (int r4 = 0; r4 < 4; r4++) {
                    const float cj = cJ[fr * 4 + r4];
                    const float lc = (cj > cI[fc]) ? acc[fr][fc][r4] * SCALE * cj : 0.0f;
                    sC += __expf(lc);
                    const int jloc = wr * 32 + fr * 16 + (lane >> 4) * 4 + r4;
                    float dr = 0.f;
                    #pragma unroll
                    for (int d = 0; d < 8; d++) dr += qv[d] * Krf[jloc][h * 8 + d];
                    sR += __expf(dr * SCALE);
                }
            pC[fc][h] = sC; pR[fc][h] = sR;
        }
    }
    #pragma unroll
    for (int fc = 0; fc < 2; fc++)
        #pragma unroll
        for (int h = 0; h < 8; h++) {
            float v = pC[fc][h]; v += __shfl_xor(v, 16); v += __shfl_xor(v, 32);
            float u = pR[fc][h]; u += __shfl_xor(u, 16); u += __shfl_xor(u, 32);
            if (lane < 16) {
                const int i = i0 + wc * 32 + fc * 16 + lane;
                const int p = blockIdx.x * 2 + wr;
                Dcpart[(p * NT + i) * 8 + h] = v;
                Drpart[(p * NT + i) * 8 + h] = u;
            }
        }
}

// ------ sparse attn @ v: one wave per row i; writes objcnt ------------------
__global__ __launch_bounds__(256) void out_small(
    const float* __restrict__ qkv_cls, const float* __restrict__ qkvn_cls,
    const float* __restrict__ qkv_reg, const float* __restrict__ qkvn_reg,
    const float* __restrict__ cls_score,
    const unsigned* __restrict__ objbits,
    const float* __restrict__ Dcpart, const float* __restrict__ Drpart,
    const float* __restrict__ x_cls, const float* __restrict__ x_reg,
    float* __restrict__ out_cls, float* __restrict__ out_reg,
    int* __restrict__ objcnt)
{
    const int i = (blockIdx.x << 2) + (threadIdx.x >> 6);  // 1536 waves
    const int l = threadIdx.x & 63;
    const int g = l >> 3;

    const float4 q4 = *(const float4*)&qkvn_cls[i * 768 + 4 * l];
    const float  qr = qkvn_reg[i * 192 + l];

    unsigned myw = (l < 48) ? objbits[i * 48 + l] : 0u;
    int cnt = __popc(myw);
    #pragma unroll
    for (int m = 1; m < 64; m <<= 1) cnt += __shfl_xor(cnt, m);

    const int s = l & 7;
    float Dcv = 0.f, Drv = 0.f;
    #pragma unroll
    for (int p6 = 0; p6 < 6; p6++) {
        const int p = s * 6 + p6;
        Dcv += Dcpart[(p * NT + i) * 8 + g];
        Drv += Drpart[(p * NT + i) * 8 + g];
    }
    Dcv += __shfl_xor(Dcv, 1); Dcv += __shfl_xor(Dcv, 2); Dcv += __shfl_xor(Dcv, 4);
    Drv += __shfl_xor(Drv, 1); Drv += __shfl_xor(Drv, 2); Drv += __shfl_xor(Drv, 4);

    float a1x = 0.f, a1y = 0.f, a1z = 0.f, a1w = 0.f;
    float a2x = 0.f, a2y = 0.f, a2z = 0.f, a2w = 0.f;
    float rr1 = 0.f, rr2 = 0.f;
    for (int w = 0; w < 48; w++) {
        unsigned bits = __shfl(myw, w);
        while (bits) {
            const int b = __ffs(bits) - 1;
            bits &= bits - 1u;
            const int j = w * 32 + b;
            const float4 k4 = *(const float4*)&qkvn_cls[j * 768 + 256 + 4 * l];
            const float4 v4 = *(const float4*)&qkv_cls [j * 768 + 512 + 4 * l];
            const float  kr = qkvn_reg[j * 192 + 64 + l];
            const float  vr = qkv_reg [j * 192 + 128 + l];
            float dc = q4.x * k4.x + q4.y * k4.y + q4.z * k4.z + q4.w * k4.w;
            dc += __shfl_xor(dc, 1); dc += __shfl_xor(dc, 2); dc += __shfl_xor(dc, 4);
            float dr = qr * kr;
            dr += __shfl_xor(dr, 1); dr += __shfl_xor(dr, 2); dr += __shfl_xor(dr, 4);
            const float cj = cls_score[j];
            const float ec = __expf(dc * SCALE * cj);   // obj => cls_mask==1
            const float er = __expf(dr * SCALE);
            a1x += ec * v4.x; a1y += ec * v4.y; a1z += ec * v4.z; a1w += ec * v4.w;
            a2x += er * v4.x; a2y += er * v4.y; a2z += er * v4.z; a2w += er * v4.w;
            rr1 += ec * vr;   rr2 += er * vr;
        }
    }
    const float iDc = 1.0f / Dcv, iDr = 1.0f / Drv;
    const float hi = 0.5f / (float)cnt;
    float4 o;
    o.x = (a1x * iDc + a2x * iDr) * hi;
    o.y = (a1y * iDc + a2y * iDr) * hi;
    o.z = (a1z * iDc + a2z * iDr) * hi;
    o.w = (a1w * iDc + a2w * iDr) * hi;
    *(float4*)&out_cls[i * 512 + 4 * l] = o;
    out_reg[i * 128 + l] = (rr1 * iDc + rr2 * iDr) * hi;
    *(float4*)&out_cls[i * 512 + 256 + 4 * l] = *(const float4*)&x_cls[i * 256 + 4 * l];
    out_reg[i * 128 + 64 + l] = x_reg[i * 64 + l];
    if (l == 0) objcnt[i] = cnt;
}

// ------ mask expansion: fully linear writes ---------------------------------
__global__ __launch_bounds__(256) void expand2(
    const unsigned* __restrict__ simbits, const unsigned* __restrict__ objbits,
    const int* __restrict__ objcnt,
    float* __restrict__ sim_out, float* __restrict__ obj_out)
{
    const int NQ = (NT * NT / 4) * 8;   // 4,718,592 float4 per array
    const int stride = gridDim.x * 256;
    for (int q = blockIdx.x * 256 + threadIdx.x; q < NQ; q += stride) {
        const int rem = q % (NT * NT / 4);     // position within one head copy
        const int i = rem / (NT / 4);
        const int j0 = (rem - i * (NT / 4)) * 4;
        const unsigned sw = simbits[i * 48 + (j0 >> 5)] >> (j0 & 31);
        const unsigned ow = objbits[i * 48 + (j0 >> 5)] >> (j0 & 31);
        const float inv = 1.0f / (float)objcnt[i];
        float4 sv, ov;
        sv.x = (sw & 1u) ? 1.f : 0.f;  ov.x = (ow & 1u) ? inv : 0.f;
        sv.y = (sw & 2u) ? 1.f : 0.f;  ov.y = (ow & 2u) ? inv : 0.f;
        sv.z = (sw & 4u) ? 1.f : 0.f;  ov.z = (ow & 4u) ? inv : 0.f;
        sv.w = (sw & 8u) ? 1.f : 0.f;  ov.w = (ow & 8u) ? inv : 0.f;
        ((float4*)sim_out)[q] = sv;
        ((float4*)obj_out)[q] = ov;
    }
}

extern "C" void kernel_launch(void* const* d_in, const int* in_sizes, int n_in,
                              void* d_out, int out_size, void* d_ws, size_t ws_size,
                              hipStream_t stream)
{
    (void)in_sizes; (void)n_in; (void)out_size; (void)ws_size;
    const float* x_cls     = (const float*)d_in[0];
    const float* x_reg     = (const float*)d_in[1];
    const float* cls_score = (const float*)d_in[2];
    const float* fg_score  = (const float*)d_in[3];
    const float* W_cls     = (const float*)d_in[4];
    const float* W_reg     = (const float*)d_in[5];

    float* out = (float*)d_out;
    float* out_cls = out;                  // 786432 floats
    float* out_reg = out + 786432;         // 196608 floats
    float* sim_out = out + 983040;         // 18874368 floats
    float* obj_out = out + 19857408;       // 18874368 floats

    // All scratch in d_ws (~21 MB)
    float* wsf = (float*)d_ws;
    float* qkv_cls  = wsf;                              // 1,179,648
    float* qkvn_cls = wsf + 1179648;                    // 1,179,648
    float* qkv_reg  = wsf + 2359296;                    //   294,912
    float* qkvn_reg = wsf + 2654208;                    //   294,912
    unsigned short* qb_cls = (unsigned short*)(wsf + 2949120);  // 1,179,648 u16
    unsigned short* qb_reg = (unsigned short*)(wsf + 3538944);  //   294,912 u16
    float* Dcpart   = wsf + 3686400;                    //   589,824 (48*1536*8)
    float* Drpart   = wsf + 4276224;                    //   589,824
    unsigned* simbits = (unsigned*)(wsf + 4866048);     //    73,728 u32
    unsigned* objbits = simbits + 73728;                //    73,728 u32
    int*      objcnt  = (int*)(objbits + 73728);        //     1,536

    gemm_norm2<<<dim3(12, 24, 2), 256, 0, stream>>>(
        x_cls, x_reg, W_cls, W_reg,
        qkv_cls, qkvn_cls, qb_cls, qkv_reg, qkvn_reg, qb_reg);
    tile2<<<dim3(24, 24), 256, 0, stream>>>(
        qb_cls, qb_reg, qkvn_reg, cls_score, fg_score,
        simbits, objbits, Dcpart, Drpart);
    out_small<<<384, 256, 0, stream>>>(
        qkv_cls, qkvn_cls, qkv_reg, qkvn_reg, cls_score,
        objbits, Dcpart, Drpart, x_cls, x_reg,
        out_cls, out_reg, objcnt);
    expand2<<<4096, 256, 0, stream>>>(
        simbits, objbits, objcnt, sim_out, obj_out);
}

// Round 9
// 83.990 us; speedup vs baseline: 3.2485x; 1.0203x over previous
//
#include <hip/hip_runtime.h>
#include <hip/hip_bf16.h>

#define NT 1536
#define SCALE 0.17677669529663687f  // (256/8)^-0.5

typedef __attribute__((ext_vector_type(8))) short bf16x8;
typedef __attribute__((ext_vector_type(4))) float f32x4;

static __device__ __forceinline__ unsigned short f2b(float x) {
    __hip_bfloat16 h = __float2bfloat16(x);
    union { __hip_bfloat16 b; unsigned short u; } cv; cv.b = h; return cv.u;
}
static __device__ __forceinline__ float b2f(unsigned short u) {
    union { float f; unsigned u; } c; c.u = ((unsigned)u) << 16; return c.f;
}

// ------ GEMM + fused per-head L2 normalize + bf16 emit (cls & reg fused) ----
__global__ __launch_bounds__(256) void gemm_norm2(
    const float* __restrict__ xc, const float* __restrict__ xr,
    const float* __restrict__ Wc, const float* __restrict__ Wr,
    float* __restrict__ qkv_c, unsigned short* __restrict__ qb_c,
    float* __restrict__ qkv_r, unsigned short* __restrict__ qb_r)
{
    const float *A, *B;
    float *qkv;
    unsigned short* qkvnb;
    int K, NN, glanes;
    if (blockIdx.z == 0) {
        A = xc; B = Wc; qkv = qkv_c; qkvnb = qb_c;
        K = 256; NN = 768; glanes = 8;
    } else {
        if (blockIdx.x >= 3) return;
        A = xr; B = Wr; qkv = qkv_r; qkvnb = qb_r;
        K = 64; NN = 192; glanes = 2;
    }
    __shared__ float As[16][68];
    __shared__ float Bs[16][68];
    const int t = threadIdx.x;
    const int tx = t & 15, ty = t >> 4;
    const int i0 = blockIdx.y * 64, j0 = blockIdx.x * 64;
    float acc[4][4] = {};
    for (int k0 = 0; k0 < K; k0 += 16) {
        float4 av = *(const float4*)&A[(i0 + (t >> 2)) * K + k0 + (t & 3) * 4];
        float4 bv = *(const float4*)&B[(k0 + (t >> 4)) * NN + j0 + tx * 4];
        __syncthreads();
        As[(t & 3) * 4 + 0][t >> 2] = av.x;
        As[(t & 3) * 4 + 1][t >> 2] = av.y;
        As[(t & 3) * 4 + 2][t >> 2] = av.z;
        As[(t & 3) * 4 + 3][t >> 2] = av.w;
        *(float4*)&Bs[t >> 4][tx * 4] = bv;
        __syncthreads();
        #pragma unroll
        for (int kk = 0; kk < 16; kk++) {
            float4 a = *(const float4*)&As[kk][ty * 4];
            float4 b = *(const float4*)&Bs[kk][tx * 4];
            float ar_[4] = {a.x, a.y, a.z, a.w};
            float br_[4] = {b.x, b.y, b.z, b.w};
            #pragma unroll
            for (int r = 0; r < 4; r++)
                #pragma unroll
                for (int c = 0; c < 4; c++)
                    acc[r][c] += ar_[r] * br_[c];
        }
    }
    #pragma unroll
    for (int r = 0; r < 4; r++) {
        const int row = i0 + ty * 4 + r, col = j0 + tx * 4;
        float4 o = {acc[r][0], acc[r][1], acc[r][2], acc[r][3]};
        *(float4*)&qkv[row * NN + col] = o;
        float s = o.x * o.x + o.y * o.y + o.z * o.z + o.w * o.w;
        for (int m = 1; m < glanes; m <<= 1) s += __shfl_xor(s, m);
        const float inv = 1.0f / sqrtf(s);
        ushort4 nb;
        nb.x = f2b(o.x * inv); nb.y = f2b(o.y * inv);
        nb.z = f2b(o.z * inv); nb.w = f2b(o.w * inv);
        *(ushort4*)&qkvnb[row * NN + col] = nb;
    }
}

// ------ fused bits + denominators (phase-B reg via zero-padded MFMA) --------
__global__ __launch_bounds__(256) void tile3(
    const unsigned short* __restrict__ qb_cls, const unsigned short* __restrict__ qb_reg,
    const float* __restrict__ cls_score, const float* __restrict__ fg_score,
    unsigned* __restrict__ simbits, unsigned* __restrict__ objbits,
    float* __restrict__ Dcpart, float* __restrict__ Drpart)
{
    __shared__ short Ai[64 * 40], Bj[64 * 40];
    __shared__ short Kr[64 * 72], Qr[64 * 72];   // reg full-K bf16 rows
    __shared__ float csi[64], csj[64], fgi[64], fgj[64];
    __shared__ unsigned simw[64][2], objw[64][2];
    const int t = threadIdx.x;
    const int lane = t & 63;
    const int wv = t >> 6, wr = wv >> 1, wc = wv & 1;
    const int i0 = blockIdx.y * 64, j0 = blockIdx.x * 64;
    if (t < 64)       { csi[t] = cls_score[i0 + t]; fgi[t] = fg_score[i0 + t]; }
    else if (t < 128) { csj[t - 64] = cls_score[j0 + t - 64]; fgj[t - 64] = fg_score[j0 + t - 64]; }
    #pragma unroll
    for (int it = 0; it < 2; it++) {
        const int u = it * 256 + t;
        const int r = u >> 3, c = u & 7;
        *(float4*)&Kr[r * 72 + c * 8] = *(const float4*)&qb_reg[(j0 + r) * 192 + 64 + c * 8];
        *(float4*)&Qr[r * 72 + c * 8] = *(const float4*)&qb_reg[(i0 + r) * 192 + 0 + c * 8];
    }
    const int sr = t >> 2, sc = t & 3;

    // ---------------- phase A: bit masks ----------------
    f32x4 ac[2][2], ar[2][2];
    #pragma unroll
    for (int a = 0; a < 2; a++)
        #pragma unroll
        for (int b = 0; b < 2; b++) { ac[a][b] = (f32x4){0,0,0,0}; ar[a][b] = (f32x4){0,0,0,0}; }
    float4 ra = *(const float4*)&qb_cls[(i0 + sr) * 768 + 512 + sc * 8];
    float4 rb = *(const float4*)&qb_cls[(j0 + sr) * 768 + 512 + sc * 8];
    for (int ks = 0; ks < 10; ks++) {
        __syncthreads();
        *(float4*)&Ai[sr * 40 + sc * 8] = ra;
        *(float4*)&Bj[sr * 40 + sc * 8] = rb;
        if (ks < 7) {
            ra = *(const float4*)&qb_cls[(i0 + sr) * 768 + 512 + (ks + 1) * 32 + sc * 8];
            rb = *(const float4*)&qb_cls[(j0 + sr) * 768 + 512 + (ks + 1) * 32 + sc * 8];
        } else if (ks < 9) {
            const int k2 = ks - 7;
            ra = *(const float4*)&qb_reg[(i0 + sr) * 192 + 128 + k2 * 32 + sc * 8];
            rb = *(const float4*)&qb_reg[(j0 + sr) * 192 + 128 + k2 * 32 + sc * 8];
        }
        __syncthreads();
        const int k8 = (lane >> 4) * 8;
        bf16x8 af[2], bf_[2];
        #pragma unroll
        for (int fr = 0; fr < 2; fr++)
            af[fr] = *(const bf16x8*)&Ai[(wr * 32 + fr * 16 + (lane & 15)) * 40 + k8];
        #pragma unroll
        for (int fc = 0; fc < 2; fc++)
            bf_[fc] = *(const bf16x8*)&Bj[(wc * 32 + fc * 16 + (lane & 15)) * 40 + k8];
        if (ks < 8) {
            #pragma unroll
            for (int fr = 0; fr < 2; fr++)
                #pragma unroll
                for (int fc = 0; fc < 2; fc++)
                    ac[fr][fc] = __builtin_amdgcn_mfma_f32_16x16x32_bf16(af[fr], bf_[fc], ac[fr][fc], 0, 0, 0);
        } else {
            #pragma unroll
            for (int fr = 0; fr < 2; fr++)
                #pragma unroll
                for (int fc = 0; fc < 2; fc++)
                    ar[fr][fc] = __builtin_amdgcn_mfma_f32_16x16x32_bf16(af[fr], bf_[fc], ar[fr][fc], 0, 0, 0);
        }
    }
    #pragma unroll
    for (int fr = 0; fr < 2; fr++)
        #pragma unroll
        for (int r4 = 0; r4 < 4; r4++) {
            const int rloc = wr * 32 + fr * 16 + (lane >> 4) * 4 + r4;
            const float ci = csi[rloc] - 0.1f, fgv = fgi[rloc] - 0.1f;
            unsigned sm[2], om[2];
            #pragma unroll
            for (int fc = 0; fc < 2; fc++) {
                const int cloc = wc * 32 + fc * 16 + (lane & 15);
                const bool clsb = csj[cloc] > ci;
                const bool fgb  = fgj[cloc] > fgv;
                const bool sim = (ac[fr][fc][r4] * 0.125f > 0.75f) && clsb && fgb;
                const bool obj = sim && (ar[fr][fc][r4] * 0.125f > 0.75f);
                unsigned long long bs = __ballot(sim);
                unsigned long long bo = __ballot(obj);
                const int g = lane >> 4;
                sm[fc] = (unsigned)((bs >> (16 * g)) & 0xFFFFull);
                om[fc] = (unsigned)((bo >> (16 * g)) & 0xFFFFull);
            }
            if ((lane & 15) == 0) {
                simw[rloc][wc] = sm[0] | (sm[1] << 16);
                objw[rloc][wc] = om[0] | (om[1] << 16);
            }
        }
    __syncthreads();
    if (t < 128) {
        const int row = t >> 1, w = t & 1;
        simbits[(i0 + row) * 48 + blockIdx.x * 2 + w] = simw[row][w];
        objbits[(i0 + row) * 48 + blockIdx.x * 2 + w] = objw[row][w];
    }

    // ---------------- phase B: denominators (cls + reg MFMA) -----------------
    float cI[2], cJ[8];
    #pragma unroll
    for (int fc = 0; fc < 2; fc++) cI[fc] = csi[wc * 32 + fc * 16 + (lane & 15)] - 0.1f;
    #pragma unroll
    for (int fr = 0; fr < 2; fr++)
        #pragma unroll
        for (int r4 = 0; r4 < 4; r4++)
            cJ[fr * 4 + r4] = csj[wr * 32 + fr * 16 + (lane >> 4) * 4 + r4];
    float pC[2][8], pR[2][8];
    const bool g0 = (lane >> 4) == 0;
    const bf16x8 zz = {0, 0, 0, 0, 0, 0, 0, 0};
    ra = *(const float4*)&qb_cls[(j0 + sr) * 768 + 256 + sc * 8];
    rb = *(const float4*)&qb_cls[(i0 + sr) * 768 + 0   + sc * 8];
    for (int h = 0; h < 8; h++) {
        __syncthreads();
        *(float4*)&Ai[sr * 40 + sc * 8] = ra;
        *(float4*)&Bj[sr * 40 + sc * 8] = rb;
        if (h < 7) {
            ra = *(const float4*)&qb_cls[(j0 + sr) * 768 + 256 + (h + 1) * 32 + sc * 8];
            rb = *(const float4*)&qb_cls[(i0 + sr) * 768 + 0   + (h + 1) * 32 + sc * 8];
        }
        __syncthreads();
        const int k8 = (lane >> 4) * 8;
        bf16x8 a[2], b[2], arg[2], brg[2];
        #pragma unroll
        for (int fr = 0; fr < 2; fr++) {
            const int row = wr * 32 + fr * 16 + (lane & 15);
            a[fr] = *(const bf16x8*)&Ai[row * 40 + k8];
            arg[fr] = g0 ? *(const bf16x8*)&Kr[row * 72 + h * 8] : zz;
        }
        #pragma unroll
        for (int fc = 0; fc < 2; fc++) {
            const int row = wc * 32 + fc * 16 + (lane & 15);
            b[fc] = *(const bf16x8*)&Bj[row * 40 + k8];
            brg[fc] = g0 ? *(const bf16x8*)&Qr[row * 72 + h * 8] : zz;
        }
        f32x4 acc[2][2], racc[2][2];
        #pragma unroll
        for (int fr = 0; fr < 2; fr++)
            #pragma unroll
            for (int fc = 0; fc < 2; fc++) {
                acc[fr][fc] = (f32x4){0,0,0,0};
                racc[fr][fc] = (f32x4){0,0,0,0};
                acc[fr][fc] = __builtin_amdgcn_mfma_f32_16x16x32_bf16(a[fr], b[fc], acc[fr][fc], 0, 0, 0);
                racc[fr][fc] = __builtin_amdgcn_mfma_f32_16x16x32_bf16(arg[fr], brg[fc], racc[fr][fc], 0, 0, 0);
            }
        #pragma unroll
        for (int fc = 0; fc < 2; fc++) {
            float sC = 0.f, sR = 0.f;
            #pragma unroll
            for (int fr = 0; fr < 2; fr++)
                #pragma unroll
                for (int r4 = 0; r4 < 4; r4++) {
                    const float cj = cJ[fr * 4 + r4];
                    const float lc = (cj > cI[fc]) ? acc[fr][fc][r4] * SCALE * cj : 0.0f;
                    sC += __expf(lc);
                    sR += __expf(racc[fr][fc][r4] * SCALE);
                }
            pC[fc][h] = sC; pR[fc][h] = sR;
        }
    }
    #pragma unroll
    for (int fc = 0; fc < 2; fc++)
        #pragma unroll
        for (int h = 0; h < 8; h++) {
            float v = pC[fc][h]; v += __shfl_xor(v, 16); v += __shfl_xor(v, 32);
            float u = pR[fc][h]; u += __shfl_xor(u, 16); u += __shfl_xor(u, 32);
            if (lane < 16) {
                const int i = i0 + wc * 32 + fc * 16 + lane;
                const int p = blockIdx.x * 2 + wr;
                Dcpart[(p * NT + i) * 8 + h] = v;
                Drpart[(p * NT + i) * 8 + h] = u;
            }
        }
}

// ------ merged finish: out rows (blocks 0..383) + mask expand (384..4479) ---
__global__ __launch_bounds__(256) void finish2(
    const float* __restrict__ qkv_cls, const unsigned short* __restrict__ qb_cls,
    const float* __restrict__ qkv_reg, const unsigned short* __restrict__ qb_reg,
    const float* __restrict__ cls_score,
    const unsigned* __restrict__ simbits, const unsigned* __restrict__ objbits,
    const float* __restrict__ Dcpart, const float* __restrict__ Drpart,
    const float* __restrict__ x_cls, const float* __restrict__ x_reg,
    float* __restrict__ out_cls, float* __restrict__ out_reg,
    float* __restrict__ sim_out, float* __restrict__ obj_out)
{
    __shared__ unsigned bw[6][48];
    __shared__ float invs[6];
    const int t = threadIdx.x;
    if (blockIdx.x < 384) {
        // ---- sparse attn-out: one wave per row ----
        const int i = (blockIdx.x << 2) + (t >> 6);
        const int l = t & 63;
        const int g = l >> 3;
        const ushort4 qu = *(const ushort4*)&qb_cls[i * 768 + 4 * l];
        const float qx = b2f(qu.x), qy = b2f(qu.y), qz = b2f(qu.z), qw = b2f(qu.w);
        const float qr = b2f(qb_reg[i * 192 + l]);
        unsigned myw = (l < 48) ? objbits[i * 48 + l] : 0u;
        int cnt = __popc(myw);
        #pragma unroll
        for (int m = 1; m < 64; m <<= 1) cnt += __shfl_xor(cnt, m);
        const int s = l & 7;
        float Dcv = 0.f, Drv = 0.f;
        #pragma unroll
        for (int p6 = 0; p6 < 6; p6++) {
            const int p = s * 6 + p6;
            Dcv += Dcpart[(p * NT + i) * 8 + g];
            Drv += Drpart[(p * NT + i) * 8 + g];
        }
        Dcv += __shfl_xor(Dcv, 1); Dcv += __shfl_xor(Dcv, 2); Dcv += __shfl_xor(Dcv, 4);
        Drv += __shfl_xor(Drv, 1); Drv += __shfl_xor(Drv, 2); Drv += __shfl_xor(Drv, 4);
        float a1x = 0.f, a1y = 0.f, a1z = 0.f, a1w = 0.f;
        float a2x = 0.f, a2y = 0.f, a2z = 0.f, a2w = 0.f;
        float rr1 = 0.f, rr2 = 0.f;
        for (int w = 0; w < 48; w++) {
            unsigned bits = __shfl(myw, w);
            while (bits) {
                const int b = __ffs(bits) - 1;
                bits &= bits - 1u;
                const int j = w * 32 + b;
                const ushort4 ku = *(const ushort4*)&qb_cls[j * 768 + 256 + 4 * l];
                const float4 v4 = *(const float4*)&qkv_cls[j * 768 + 512 + 4 * l];
                const float kr = b2f(qb_reg[j * 192 + 64 + l]);
                const float vr = qkv_reg[j * 192 + 128 + l];
                float dc = qx * b2f(ku.x) + qy * b2f(ku.y) + qz * b2f(ku.z) + qw * b2f(ku.w);
                dc += __shfl_xor(dc, 1); dc += __shfl_xor(dc, 2); dc += __shfl_xor(dc, 4);
                float dr = qr * kr;
                dr += __shfl_xor(dr, 1); dr += __shfl_xor(dr, 2); dr += __shfl_xor(dr, 4);
                const float cj = cls_score[j];
                const float ec = __expf(dc * SCALE * cj);   // obj => cls_mask==1
                const float er = __expf(dr * SCALE);
                a1x += ec * v4.x; a1y += ec * v4.y; a1z += ec * v4.z; a1w += ec * v4.w;
                a2x += er * v4.x; a2y += er * v4.y; a2z += er * v4.z; a2w += er * v4.w;
                rr1 += ec * vr;   rr2 += er * vr;
            }
        }
        const float iDc = 1.0f / Dcv, iDr = 1.0f / Drv;
        const float hi = 0.5f / (float)cnt;
        float4 o;
        o.x = (a1x * iDc + a2x * iDr) * hi;
        o.y = (a1y * iDc + a2y * iDr) * hi;
        o.z = (a1z * iDc + a2z * iDr) * hi;
        o.w = (a1w * iDc + a2w * iDr) * hi;
        *(float4*)&out_cls[i * 512 + 4 * l] = o;
        out_reg[i * 128 + l] = (rr1 * iDc + rr2 * iDr) * hi;
        *(float4*)&out_cls[i * 512 + 256 + 4 * l] = *(const float4*)&x_cls[i * 256 + 4 * l];
        out_reg[i * 128 + 64 + l] = x_reg[i * 64 + l];
    } else {
        // ---- mask expansion: 6 contiguous rows of one head-copy ----
        const int eb = blockIdx.x - 384;        // 0..4095
        const int arr = eb >> 11;               // 0: sim, 1: obj
        const int rem = eb & 2047;
        const int copy = rem >> 8;              // 0..7
        const int blk = rem & 255;
        const int r0 = blk * 6;
        const unsigned* src = arr ? objbits : simbits;
        for (int u = t; u < 288; u += 256) bw[u / 48][u % 48] = src[(r0 + u / 48) * 48 + (u % 48)];
        __syncthreads();
        if (t < 6) {
            int c = 0;
            #pragma unroll 8
            for (int w = 0; w < 48; w++) c += __popc(bw[t][w]);
            invs[t] = 1.0f / (float)c;
        }
        __syncthreads();
        float4* dst = (float4*)((arr ? obj_out : sim_out) + (size_t)copy * NT * NT + (size_t)r0 * NT);
        #pragma unroll
        for (int rpt = 0; rpt < 9; rpt++) {
            const int u = rpt * 256 + t;        // 0..2303
            const int row = u / 384;
            const int c4 = u - row * 384;
            const int j0 = c4 * 4;
            const unsigned w = bw[row][j0 >> 5] >> (j0 & 31);
            const float on = arr ? invs[row] : 1.0f;
            float4 v;
            v.x = (w & 1u) ? on : 0.f;
            v.y = (w & 2u) ? on : 0.f;
            v.z = (w & 4u) ? on : 0.f;
            v.w = (w & 8u) ? on : 0.f;
            dst[row * 384 + c4] = v;
        }
    }
}

extern "C" void kernel_launch(void* const* d_in, const int* in_sizes, int n_in,
                              void* d_out, int out_size, void* d_ws, size_t ws_size,
                              hipStream_t stream)
{
    (void)in_sizes; (void)n_in; (void)out_size; (void)ws_size;
    const float* x_cls     = (const float*)d_in[0];
    const float* x_reg     = (const float*)d_in[1];
    const float* cls_score = (const float*)d_in[2];
    const float* fg_score  = (const float*)d_in[3];
    const float* W_cls     = (const float*)d_in[4];
    const float* W_reg     = (const float*)d_in[5];

    float* out = (float*)d_out;
    float* out_cls = out;                  // 786432 floats
    float* out_reg = out + 786432;         // 196608 floats
    float* sim_out = out + 983040;         // 18874368 floats
    float* obj_out = out + 19857408;       // 18874368 floats

    // Scratch in d_ws (~14 MB)
    float* wsf = (float*)d_ws;
    float* qkv_cls = wsf;                               // 1,179,648 f
    float* qkv_reg = wsf + 1179648;                     //   294,912 f
    float* Dcpart  = wsf + 1474560;                     //   589,824 f
    float* Drpart  = wsf + 2064384;                     //   589,824 f
    unsigned short* qb_cls = (unsigned short*)(wsf + 2654208);  // 1,179,648 u16
    unsigned short* qb_reg = (unsigned short*)(wsf + 3244032);  //   294,912 u16
    unsigned* simbits = (unsigned*)(wsf + 3391488);     //    73,728 u32
    unsigned* objbits = simbits + 73728;                //    73,728 u32

    gemm_norm2<<<dim3(12, 24, 2), 256, 0, stream>>>(
        x_cls, x_reg, W_cls, W_reg,
        qkv_cls, qb_cls, qkv_reg, qb_reg);
    tile3<<<dim3(24, 24), 256, 0, stream>>>(
        qb_cls, qb_reg, cls_score, fg_score,
        simbits, objbits, Dcpart, Drpart);
    finish2<<<4480, 256, 0, stream>>>(
        qkv_cls, qb_cls, qkv_reg, qb_reg, cls_score,
        simbits, objbits, Dcpart, Drpart, x_cls, x_reg,
        out_cls, out_reg, sim_out, obj_out);
}